// Round 6
// baseline (341.558 us; speedup 1.0000x reference)
//
#include <hip/hip_runtime.h>

typedef __attribute__((ext_vector_type(8))) short bf16x8;
typedef __attribute__((ext_vector_type(4))) float f32x4;
typedef __attribute__((ext_vector_type(4))) int   i32x4;

#define PI_F 3.14159265358979323846f
#define C128 0.0490873852123405f      /* 2*pi/128 */
#define INV_SQRT128 0.0883883476483184f
#define INV128 0.0078125f

#define NB 8
#define NC 256
#define NH 128
#define NW 128
#define IMG 16384
#define NIMG 2048

// GH per-image layout (floats, stride 3200):
//  [0..1535]    G  : [w6][re/im][128]   (w = 61..66)
//  [1536..3071] Hh : [z6][re/im][128]   (z = 61..66)
//  [3072..3143] Fc : 36 complex (w6 x z6)
//  [3144..3192] magC: 49
#define GH_STRIDE 3200
// AB per-image layout (floats, stride 3072)
#define AB_STRIDE 3072

__device__ __forceinline__ unsigned short f2bf(float f){
  unsigned int u = __float_as_uint(f);
  u += 0x7FFFu + ((u >> 16) & 1u);
  return (unsigned short)(u >> 16);
}
__device__ __forceinline__ float bf2f(unsigned short u){
  return __uint_as_float(((unsigned int)u) << 16);
}

__device__ __constant__ int c_pcnt[6] = {1,2,3,3,2,1};
__device__ __constant__ int c_pdp0[6] = {6,5,4,0,0,0};

#define COS1 0.9987954562051724f
#define SIN1 0.0490676743274180f
#define K1CH (2.0f*COS1)

// LDS float offsets for K1 (total 10240 floats = 40960 B -> 4 blocks/CU)
#define SM_GG   8320     /* Gg [4][2][128] = 1024 floats */
#define SM_HLR  9344     /* HloR [4][128]  = 512 floats  */
#define SM_HLI  9856     /* HloI [3][128]  = 384 floats  */
#define SM_SCRG 1920     /* col scratch (aliases xs)     */

// =====================================================================
// K1: per image: high-freq partial DFTs G,Hh + corner Fc + magC(49).
// 512 threads: 256 row-DFT (half-row each), 256 col-DFT (half-col each).
// Tails use skewed LDS access (bank-conflict-free).
// =====================================================================
__global__ void __launch_bounds__(512, 8) K1(const float* __restrict__ xlow,
                                             float* __restrict__ GH){
  __shared__ float smem[10240];
  unsigned short* xs = (unsigned short*)smem;   // stride 130 u16
  const int tid = threadIdx.x;
  const int img = blockIdx.x;
  float* ghb = GH + (size_t)img*GH_STRIDE;

  // ---- stage x -> bf16 LDS ----
  {
    const float4* xp = (const float4*)(xlow + (size_t)img*IMG);
    #pragma unroll
    for (int k=0; k<8; ++k){
      int e4 = k*512 + tid;
      float4 v = xp[e4];
      int r = e4 >> 5, c = (e4 & 31)*4;
      unsigned int pw0 = (unsigned int)f2bf(v.x) | ((unsigned int)f2bf(v.y) << 16);
      unsigned int pw1 = (unsigned int)f2bf(v.z) | ((unsigned int)f2bf(v.w) << 16);
      *(unsigned int*)(&xs[r*130 + c    ]) = pw0;
      *(unsigned int*)(&xs[r*130 + c + 2]) = pw1;
    }
  }
  __syncthreads();

  float acc[14];
  #pragma unroll
  for (int i=0;i<14;++i) acc[i]=0.f;

  const int isRow = (tid < 256);
  const int lid  = isRow ? tid : (tid-256);
  const int idx  = lid & 127;
  const int half = lid >> 7;

  {
    const float sg0 = half ? -1.f : 1.f;
    float cp = sg0, sp = 0.f;
    float cn = sg0*COS1, sn = sg0*SIN1;

#define K1_ACCUM(xv, cc, ss)                                   \
    {                                                          \
      float t2 = cc + cc;                                      \
      float c2 = fmaf(t2, cc, -1.f);                           \
      float s2 = t2 * ss;                                      \
      float c3 = fmaf(t2, c2, -cc);                            \
      float s3 = fmaf(t2, s2, -ss);                            \
      acc[0 + PARITY] += xv;                                   \
      acc[2 + PARITY*2]  = fmaf(xv, cc, acc[2 + PARITY*2]);    \
      acc[3 + PARITY*2]  = fmaf(xv, ss, acc[3 + PARITY*2]);    \
      acc[6 + PARITY*2]  = fmaf(xv, c2, acc[6 + PARITY*2]);    \
      acc[7 + PARITY*2]  = fmaf(xv, s2, acc[7 + PARITY*2]);    \
      acc[10 + PARITY*2] = fmaf(xv, c3, acc[10 + PARITY*2]);   \
      acc[11 + PARITY*2] = fmaf(xv, s3, acc[11 + PARITY*2]);   \
    }

    if (isRow){
      const unsigned short* xr = &xs[idx*130 + half*64];
      #pragma unroll 4
      for (int j=0; j<32; ++j){
        unsigned int pk = *(const unsigned int*)(&xr[2*j]);
        float xe = __uint_as_float(pk << 16);
        float xo = __uint_as_float(pk & 0xffff0000u);
#define PARITY 0
        K1_ACCUM(xe, cp, sp)
#undef PARITY
#define PARITY 1
        K1_ACCUM(xo, cn, sn)
#undef PARITY
        float cpn = fmaf(K1CH, cn, -cp);
        float spn = fmaf(K1CH, sn, -sp);
        float cnn = fmaf(K1CH, cpn, -cn);
        float snn = fmaf(K1CH, spn, -sn);
        cp = cpn; sp = spn; cn = cnn; sn = snn;
      }
    } else {
      const unsigned short* xc = &xs[half*64*130 + idx];
      #pragma unroll 4
      for (int j=0; j<32; ++j){
        float xe = bf2f(xc[(2*j  )*130]);
        float xo = bf2f(xc[(2*j+1)*130]);
#define PARITY 0
        K1_ACCUM(xe, cp, sp)
#undef PARITY
#define PARITY 1
        K1_ACCUM(xo, cn, sn)
#undef PARITY
        float cpn = fmaf(K1CH, cn, -cp);
        float spn = fmaf(K1CH, sn, -sp);
        float cnn = fmaf(K1CH, cpn, -cn);
        float snn = fmaf(K1CH, spn, -sn);
        cp = cpn; sp = spn; cn = cnn; sn = snn;
      }
    }
#undef K1_ACCUM
  }
  __syncthreads();     // xs reads done; scratch may overwrite

  const int scrbase = (isRow ? 0 : SM_SCRG) + idx*15;
  if (half){
    #pragma unroll
    for (int i=0;i<14;++i) smem[scrbase+i] = acc[i];
  }
  __syncthreads();
  if (!half){
    #pragma unroll
    for (int i=0;i<14;++i) acc[i] += smem[scrbase+i];
    float A0e=acc[0],A0o=acc[1],Ce1=acc[2],Se1=acc[3],Co1=acc[4],So1=acc[5],
          Ce2=acc[6],Se2=acc[7],Co2=acc[8],So2=acc[9],
          Ce3=acc[10],Se3=acc[11],Co3=acc[12],So3=acc[13];
    float d0  = A0e-A0o;
    float dc1 = Ce1-Co1, ds1 = Se1-So1;
    float dc2 = Ce2-Co2, ds2 = Se2-So2;
    float dc3 = Ce3-Co3, ds3 = Se3-So3;
    float* gp = ghb + (isRow ? 1536 : 0);
    const int k = idx;
    gp[(0*2+0)*128+k] = dc3*INV_SQRT128;  gp[(0*2+1)*128+k] =  ds3*INV_SQRT128;
    gp[(1*2+0)*128+k] = dc2*INV_SQRT128;  gp[(1*2+1)*128+k] =  ds2*INV_SQRT128;
    gp[(2*2+0)*128+k] = dc1*INV_SQRT128;  gp[(2*2+1)*128+k] =  ds1*INV_SQRT128;
    gp[(3*2+0)*128+k] = d0 *INV_SQRT128;  gp[(3*2+1)*128+k] =  0.f;
    gp[(4*2+0)*128+k] = dc1*INV_SQRT128;  gp[(4*2+1)*128+k] = -ds1*INV_SQRT128;
    gp[(5*2+0)*128+k] = dc2*INV_SQRT128;  gp[(5*2+1)*128+k] = -ds2*INV_SQRT128;
    if (isRow){
      smem[SM_HLR + 0*128 + k] = A0e+A0o;
      smem[SM_HLR + 1*128 + k] = Ce1+Co1;
      smem[SM_HLR + 2*128 + k] = Ce2+Co2;
      smem[SM_HLR + 3*128 + k] = Ce3+Co3;
      smem[SM_HLI + 0*128 + k] = -(Se1+So1);
      smem[SM_HLI + 1*128 + k] = -(Se2+So2);
      smem[SM_HLI + 2*128 + k] = -(Se3+So3);
    } else {
      smem[SM_GG + (0*2+0)*128 + k] = dc3;  smem[SM_GG + (0*2+1)*128 + k] = ds3;
      smem[SM_GG + (1*2+0)*128 + k] = dc2;  smem[SM_GG + (1*2+1)*128 + k] = ds2;
      smem[SM_GG + (2*2+0)*128 + k] = dc1;  smem[SM_GG + (2*2+1)*128 + k] = ds1;
      smem[SM_GG + (3*2+0)*128 + k] = d0;   smem[SM_GG + (3*2+1)*128 + k] = 0.f;
    }
  }
  __syncthreads();

  // ---- Fc tail: 36 outputs x 4 chunks, skewed (bank-conflict-free) ----
  if (tid < 144){
    int out = tid >> 2, chunk = tid & 3;
    int wi = out/6, zi = out%6, z = 61+zi;
    int wsrc = (wi<4) ? wi : (wi==4 ? 2 : 1);
    float isg = (wi<4) ? 1.f : -1.f;
    float fR=0.f, fI=0.f;
    for (int ii=0; ii<32; ++ii){
      int c = chunk*32 + ((ii + tid) & 31);
      float gR = smem[SM_GG + (wsrc*2  )*128 + c];
      float gI = isg*smem[SM_GG + (wsrc*2+1)*128 + c];
      int m = (z*c) & 127;
      float ts, tc; __sincosf((float)m*C128, &ts, &tc);
      fR += gR*tc + gI*ts;
      fI += gI*tc - gR*ts;
    }
    fR += __shfl_xor(fR,1); fI += __shfl_xor(fI,1);
    fR += __shfl_xor(fR,2); fI += __shfl_xor(fI,2);
    if (chunk==0){
      ghb[3072 + out*2]     = fR * INV128;
      ghb[3072 + out*2 + 1] = fI * INV128;
    }
  }
  // ---- magC tail: 49 outputs x 4 chunks, skewed ----
  if (tid >= 256 && tid < 452){
    int i = (tid-256) >> 2, chunk = (tid-256) & 3;
    int u = i/7 - 3, v = i%7 - 3;
    int va = v < 0 ? -v : v;
    float vsg = v < 0 ? -1.f : 1.f;
    float fR=0.f, fI=0.f;
    for (int ii=0; ii<32; ++ii){
      int r = chunk*32 + ((ii + tid) & 31);
      float hR = smem[SM_HLR + va*128 + r];
      float hI = (va==0) ? 0.f : vsg*smem[SM_HLI + (va-1)*128 + r];
      int m = ((u*r) % 128 + 128) & 127;
      float ts, tc; __sincosf((float)m*C128, &ts, &tc);
      fR += hR*tc + hI*ts;
      fI += hI*tc - hR*ts;
    }
    fR += __shfl_xor(fR,1); fI += __shfl_xor(fI,1);
    fR += __shfl_xor(fR,2); fI += __shfl_xor(fI,2);
    if (chunk==0){
      fR *= INV128; fI *= INV128;
      ghb[3144 + i] = sqrtf(fR*fR + fI*fI);
    }
  }
}

// =====================================================================
// K_mlp
// =====================================================================
__global__ void __launch_bounds__(64) K_mlp(const float* __restrict__ GH,
                                            const float* __restrict__ w1,
                                            const float* __restrict__ b1,
                                            const float* __restrict__ w2,
                                            const float* __restrict__ b2,
                                            float* __restrict__ kern){
  __shared__ float flat[49];
  __shared__ float hh[32];
  const int b = blockIdx.x, tid = threadIdx.x;
  if (tid < 49){
    float s = 0.f;
    for (int c=0; c<256; ++c)
      s += GH[(size_t)(b*256 + c)*GH_STRIDE + 3144 + tid];
    flat[tid] = s * (1.0f/256.0f);
  }
  __syncthreads();
  if (tid < 32){
    float s = b1[tid];
    for (int i=0; i<49; ++i) s += flat[i]*w1[tid*49+i];
    hh[tid] = fmaxf(s, 0.f);
  }
  __syncthreads();
  if (tid == 0){
    float p[3];
    #pragma unroll
    for (int k=0; k<3; ++k){
      float s = b2[k];
      for (int j=0; j<32; ++j) s += hh[j]*w2[k*32+j];
      p[k] = s;
    }
    float theta = atan2f(p[0], p[1])*0.5f + 1.57079632679489662f;
    float ct = cosf(theta), st = sinf(theta);
    float l1 = expf(p[2]);
    float l2 = 1.0f/(l1 + 1e-8f);
    float inv1 = 1.0f/(2.0f*l1*l1);
    float inv2 = 1.0f/(2.0f*l2*l2);
    float sum = 0.f;
    for (int i=0; i<7; ++i) for (int j=0; j<7; ++j){
      float yy = (float)(i-3), xx = (float)(j-3);
      float xr =  xx*ct + yy*st;
      float yr = -xx*st + yy*ct;
      sum += expf(-(xr*xr*inv1 + yr*yr*inv2));
    }
    float inv = 1.0f/(sum + 1e-8f);
    for (int i=0; i<7; ++i) for (int j=0; j<7; ++j){
      float yy = (float)(i-3), xx = (float)(j-3);
      float xr =  xx*ct + yy*st;
      float yr = -xx*st + yy*ct;
      kern[b*49 + i*7 + j] = expf(-(xr*xr*inv1 + yr*yr*inv2)) * inv;
    }
  }
}

// =====================================================================
// K3: per batch: kappa/lambda tables + W field
// =====================================================================
__global__ void __launch_bounds__(256) K3(const float* __restrict__ kern,
                                          float* __restrict__ KL,
                                          float* __restrict__ W){
  __shared__ float twc[128], tws[128], kl[49];
  __shared__ float kapl[7][2][128];
  const int b = blockIdx.x, tid = threadIdx.x;
  if (tid < 128){
    float s,c; __sincosf((float)tid*C128, &s, &c);
    twc[tid]=c; tws[tid]=s;
  }
  if (tid < 49) kl[tid] = kern[b*49 + tid];
  __syncthreads();
  if (tid < 128){
    const int c = tid;
    float* klb = KL + (size_t)b*3584;
    #pragma unroll
    for (int dp=0; dp<7; ++dp){
      float kR=0.f, kI=0.f;
      #pragma unroll
      for (int dq=0; dq<7; ++dq){
        int m = (((dq-3)*c) % 128 + 128) & 127;
        float kv = kl[dp*7+dq];
        kR += kv*twc[m]; kI -= kv*tws[m];
      }
      klb[(dp*2  )*128 + c] = kR;
      klb[(dp*2+1)*128 + c] = kI;
      kapl[dp][0][c] = kR; kapl[dp][1][c] = kI;
    }
    const int r = tid;
    #pragma unroll
    for (int dq=0; dq<7; ++dq){
      float lR=0.f, lI=0.f;
      #pragma unroll
      for (int dp=0; dp<7; ++dp){
        int m = (((dp-3)*r) % 128 + 128) & 127;
        float kv = kl[dp*7+dq];
        lR += kv*twc[m]; lI -= kv*tws[m];
      }
      klb[1792 + (dq*2  )*128 + r] = lR;
      klb[1792 + (dq*2+1)*128 + r] = lI;
    }
  }
  __syncthreads();
  for (int k=0;k<64;++k){
    int px = k*256 + tid;
    int r = px >> 7, c = px & 127;
    float w = 0.f;
    #pragma unroll
    for (int dp=0; dp<7; ++dp){
      int m = (((dp-3)*r) % 128 + 128) & 127;
      w += twc[m]*kapl[dp][0][c] + tws[m]*kapl[dp][1][c];
    }
    W[(size_t)b*IMG + px] = w;
  }
}

// =====================================================================
// K_tab: per image: Abar (corner-folded) and Bbar tables
// =====================================================================
__global__ void __launch_bounds__(128) K_tab(const float* __restrict__ GH,
                                             const float* __restrict__ KL,
                                             const float* __restrict__ kern,
                                             float* __restrict__ AB){
  __shared__ float dRe[36], dIm[36], kl[49];
  const int tid = threadIdx.x;
  const int img = blockIdx.x, b = img >> 8;
  const float* ghb = GH + (size_t)img*GH_STRIDE;
  const float* klb = KL + (size_t)b*3584;
  float* abb = AB + (size_t)img*AB_STRIDE;

  if (tid < 49) kl[tid] = kern[b*49 + tid];
  __syncthreads();
  if (tid < 36){
    int si = tid/6, ti = tid%6;
    float dR=0.f, dI=0.f;
    for (int j=0; j<c_pcnt[si]; ++j){
      int dp = c_pdp0[si] + j;
      int wi = (si-3) + dp;
      for (int l=0; l<c_pcnt[ti]; ++l){
        int dq = c_pdp0[ti] + l;
        int zi = (ti-3) + dq;
        float kv = kl[dp*7+dq];
        dR += kv * ghb[3072 + (wi*6+zi)*2];
        dI += kv * ghb[3072 + (wi*6+zi)*2 + 1];
      }
    }
    dRe[tid] = dR; dIm[tid] = dI;
  }
  __syncthreads();

  const int c = tid;
  float s1,c1; __sincosf((float)c*C128, &s1, &c1);
  float c2 = c1*c1 - s1*s1, s2 = 2.f*c1*s1;
  float c3 = c1*c2 - s1*s2, s3 = s1*c2 + c1*s2;
  float ct[6] = {c3,c2,c1,1.f,c1,c2};
  float st[6] = {-s3,-s2,-s1,0.f,s1,s2};
  float sgnc = (c & 1) ? -1.f : 1.f;

  float gr[6], gi[6], kr[7], ki[7];
  #pragma unroll
  for (int w=0;w<6;++w){ gr[w]=ghb[(w*2)*128+c]; gi[w]=ghb[(w*2+1)*128+c]; }
  #pragma unroll
  for (int dp=0;dp<7;++dp){ kr[dp]=klb[(dp*2)*128+c]; ki[dp]=klb[(dp*2+1)*128+c]; }

  #pragma unroll
  for (int si=0; si<6; ++si){
    float dR=0.f, dI=0.f;
    for (int j=0; j<c_pcnt[si]; ++j){
      int dp = c_pdp0[si] + j;
      int w = (si-3) + dp;
      dR += kr[dp]*gr[w] - ki[dp]*gi[w];
      dI += kr[dp]*gi[w] + ki[dp]*gr[w];
    }
    float corrR=0.f, corrI=0.f;
    #pragma unroll
    for (int ti=0; ti<6; ++ti){
      float DR = dRe[si*6+ti], DI = dIm[si*6+ti];
      corrR += DR*ct[ti] - DI*st[ti];
      corrI += DR*st[ti] + DI*ct[ti];
    }
    abb[(si*2  )*128 + c] = INV_SQRT128*dR - INV128*sgnc*corrR;
    abb[(si*2+1)*128 + c] = INV_SQRT128*dI - INV128*sgnc*corrI;
  }

  const int r = tid;
  float hr[6], hi_[6], lr[7], li[7];
  #pragma unroll
  for (int z=0;z<6;++z){ hr[z]=ghb[1536+(z*2)*128+r]; hi_[z]=ghb[1536+(z*2+1)*128+r]; }
  #pragma unroll
  for (int dq=0;dq<7;++dq){ lr[dq]=klb[1792+(dq*2)*128+r]; li[dq]=klb[1792+(dq*2+1)*128+r]; }
  #pragma unroll
  for (int ti=0; ti<6; ++ti){
    float bR=0.f, bI=0.f;
    for (int l=0; l<c_pcnt[ti]; ++l){
      int dq = c_pdp0[ti] + l;
      int z = (ti-3) + dq;
      bR += lr[dq]*hr[z] - li[dq]*hi_[z];
      bI += lr[dq]*hi_[z] + li[dq]*hr[z];
    }
    abb[1536 + r*12 + ti*2]     = INV_SQRT128*bR;
    abb[1536 + r*12 + ti*2 + 1] = INV_SQRT128*bI;
  }
}

// =====================================================================
// K4: per image: filt = x*W - E  (bf16 out), float2 per lane
// =====================================================================
__global__ void __launch_bounds__(256) K4(const float* __restrict__ xlow,
                                          const float* __restrict__ W,
                                          const float* __restrict__ AB,
                                          unsigned short* __restrict__ filt){
  const int tid = threadIdx.x;
  const int img = blockIdx.x, b = img >> 8;
  const int c0 = (tid & 63)*2, grp = tid >> 6;
  const float* abb = AB + (size_t)img*AB_STRIDE;
  const float* xim = xlow + (size_t)img*IMG;
  const float* Wb  = W + (size_t)b*IMG;
  unsigned short* fim = filt + (size_t)img*IMG;

  float ar[2][6], ai[2][6], ctc[2][6], stc[2][6];
  #pragma unroll
  for (int col=0; col<2; ++col){
    int c = c0 + col;
    #pragma unroll
    for (int si=0;si<6;++si){ ar[col][si]=abb[(si*2)*128+c]; ai[col][si]=abb[(si*2+1)*128+c]; }
    float s1,c1; __sincosf((float)c*C128, &s1, &c1);
    float c2 = c1*c1 - s1*s1, s2 = 2.f*c1*s1;
    float c3 = c1*c2 - s1*s2, s3 = s1*c2 + c1*s2;
    ctc[col][0]=c3; ctc[col][1]=c2; ctc[col][2]=c1; ctc[col][3]=1.f; ctc[col][4]=c1; ctc[col][5]=c2;
    stc[col][0]=-s3; stc[col][1]=-s2; stc[col][2]=-s1; stc[col][3]=0.f; stc[col][4]=s1; stc[col][5]=s2;
  }

  for (int k=0;k<32;++k){
    int ru = __builtin_amdgcn_readfirstlane(grp*32 + k);
    const float* brow = abb + 1536 + ru*12;
    float4 b0 = *(const float4*)(brow);
    float4 b1 = *(const float4*)(brow+4);
    float4 b2 = *(const float4*)(brow+8);
    float rs1,rc1; __sincosf((float)ru*C128, &rs1, &rc1);
    float rc2 = rc1*rc1 - rs1*rs1, rs2 = 2.f*rc1*rs1;
    float rc3 = rc1*rc2 - rs1*rs2, rs3 = rs1*rc2 + rc1*rs2;
    float rcs[6] = {rc3,rc2,rc1,1.f,rc1,rc2};
    float rss[6] = {-rs3,-rs2,-rs1,0.f,rs1,rs2};

    float ER0 = 0.f, ER1 = 0.f;
    #pragma unroll
    for (int si=0;si<6;++si){
      ER0 += rcs[si]*ar[0][si] - rss[si]*ai[0][si];
      ER1 += rcs[si]*ar[1][si] - rss[si]*ai[1][si];
    }
    float rsg = (ru & 1) ? -1.f : 1.f;
    ER0 *= rsg; ER1 *= rsg;

    float bRv[6] = {b0.x, b0.z, b1.x, b1.z, b2.x, b2.z};
    float bIv[6] = {b0.y, b0.w, b1.y, b1.w, b2.y, b2.w};
    float EC0 = 0.f, EC1 = 0.f;
    #pragma unroll
    for (int ti=0;ti<6;++ti){
      EC0 += ctc[0][ti]*bRv[ti] - stc[0][ti]*bIv[ti];
      EC1 += ctc[1][ti]*bRv[ti] - stc[1][ti]*bIv[ti];
    }
    int px = ru*128 + c0;
    float2 xv = *(const float2*)(&xim[px]);
    float2 wv = *(const float2*)(&Wb[px]);
    float v0 = xv.x*wv.x - ER0 - EC0;
    float v1 = xv.y*wv.y - ER1 + EC1;
    unsigned int pack = ((unsigned int)f2bf(v1) << 16) | (unsigned int)f2bf(v0);
    *(unsigned int*)(&fim[px]) = pack;
  }
}

// =====================================================================
// K_w: refine_w f32 -> bf16
// =====================================================================
__global__ void __launch_bounds__(256) K_w(const float* __restrict__ rw,
                                           unsigned short* __restrict__ rwbf){
  int i = blockIdx.x*256 + threadIdx.x;
  rwbf[i] = f2bf(rw[i]);
}

// =====================================================================
// K_trans: filt [b][c][p] -> filtT [b][p][c], 64x64 tiles, ushort4 I/O
// =====================================================================
__global__ void __launch_bounds__(256) K_trans(const unsigned short* __restrict__ in,
                                               unsigned short* __restrict__ outT){
  __shared__ unsigned short tile[64*68];    // [p][c], stride 68
  const int p0 = blockIdx.x * 64;
  const int c0 = blockIdx.y * 64;
  const int b  = blockIdx.z;
  const int tid = threadIdx.x;
  const int lo = tid >> 4;
  const int q4 = (tid & 15) * 4;

  #pragma unroll
  for (int pass=0; pass<4; ++pass){
    int cc = lo + pass*16;
    ushort4 v = *(const ushort4*)(&in[((size_t)b*NC + c0 + cc)*IMG + p0 + q4]);
    tile[(q4+0)*68 + cc] = v.x;
    tile[(q4+1)*68 + cc] = v.y;
    tile[(q4+2)*68 + cc] = v.z;
    tile[(q4+3)*68 + cc] = v.w;
  }
  __syncthreads();
  #pragma unroll
  for (int pass=0; pass<4; ++pass){
    int pp = lo + pass*16;
    ushort4 v = *(const ushort4*)(&tile[pp*68 + q4]);
    *(ushort4*)(&outT[((size_t)b*IMG + p0 + pp)*NC + c0 + q4]) = v;
  }
}

// =====================================================================
// K_gemm: out[b,o,p] = sum_c rw[o,c]*filt[b,c,p] + bilinear(x_high)
// Pure-register GEMM: A and B fragments loaded directly from global
// (A: L2-hot rwbf; B: filtT rows, k-contiguous). No LDS / barriers in
// the K-loop; 2-deep register ping-pong. LDS used only for the fused
// upsample epilogue (xhigh rows staged as bf16, stride 132).
// =====================================================================
__global__ void __launch_bounds__(256) K_gemm(const unsigned short* __restrict__ rwbf,
                                              const unsigned short* __restrict__ filtT,
                                              const float* __restrict__ xhigh,
                                              float* __restrict__ out){
  __shared__ unsigned short epi[128*132];   // 33792 B
  const int tid = threadIdx.x, lane = tid & 63, wv = tid >> 6;
  const int wr = wv >> 1, wc = wv & 1;
  const int xg = blockIdx.x;
  const int g16 = xg >> 4, i16 = xg & 15;
  const int ot = i16 >> 3, pt = (g16 << 3) | (i16 & 7);
  const int b = blockIdx.z;
  const int p0 = pt*128, o0 = ot*128;
  const int g = lane >> 4, r16 = lane & 15;

  const unsigned short* aBase[4];
  const unsigned short* bBase[4];
  #pragma unroll
  for (int m=0;m<4;++m) aBase[m] = &rwbf[(size_t)(o0 + wr*64 + m*16 + r16)*256 + g*8];
  #pragma unroll
  for (int n=0;n<4;++n) bBase[n] = &filtT[((size_t)b*IMG + p0 + wc*64 + n*16 + r16)*256 + g*8];

  f32x4 acc[4][4];
  #pragma unroll
  for (int m=0;m<4;++m)
    #pragma unroll
    for (int n=0;n<4;++n){ f32x4 z = {0.f,0.f,0.f,0.f}; acc[m][n] = z; }

  bf16x8 aReg[2][4], bReg[2][4];
  #pragma unroll
  for (int m=0;m<4;++m) aReg[0][m] = *(const bf16x8*)(aBase[m]);
  #pragma unroll
  for (int n=0;n<4;++n) bReg[0][n] = *(const bf16x8*)(bBase[n]);

  #pragma unroll
  for (int ks=0; ks<8; ++ks){
    const int cur = ks & 1, nxt = cur ^ 1;
    if (ks < 7){
      #pragma unroll
      for (int m=0;m<4;++m) aReg[nxt][m] = *(const bf16x8*)(aBase[m] + (ks+1)*32);
      #pragma unroll
      for (int n=0;n<4;++n) bReg[nxt][n] = *(const bf16x8*)(bBase[n] + (ks+1)*32);
    }
    #pragma unroll
    for (int m=0;m<4;++m)
      #pragma unroll
      for (int n=0;n<4;++n)
        acc[m][n] = __builtin_amdgcn_mfma_f32_16x16x32_bf16(aReg[cur][m], bReg[cur][n], acc[m][n], 0, 0, 0);
  }

  // ---- fused bilinear upsample epilogue ----
  const int y = pt;
  float fy = 0.5f*(float)y - 0.25f;
  int iyf = (int)floorf(fy);
  float ty = fy - (float)iyf;
  int iy0 = iyf < 0 ? 0 : iyf;
  int iy1 = (iyf+1) > 63 ? 63 : (iyf+1);
  float wy1 = ty, wy0 = 1.0f - ty;

  {
    int ol = tid >> 1, half = tid & 1;
    const float* s0 = &xhigh[((size_t)(b*NC + o0 + ol)*64 + iy0)*64 + half*32];
    const float* s1 = &xhigh[((size_t)(b*NC + o0 + ol)*64 + iy1)*64 + half*32];
    unsigned short* d0 = &epi[ol*132 + half*32];
    unsigned short* d1 = &epi[ol*132 + 64 + half*32];
    #pragma unroll
    for (int i=0;i<8;++i){
      float4 v0 = *(const float4*)(s0 + i*4);
      float4 v1 = *(const float4*)(s1 + i*4);
      *(unsigned int*)(&d0[i*4  ]) = (unsigned int)f2bf(v0.x) | ((unsigned int)f2bf(v0.y) << 16);
      *(unsigned int*)(&d0[i*4+2]) = (unsigned int)f2bf(v0.z) | ((unsigned int)f2bf(v0.w) << 16);
      *(unsigned int*)(&d1[i*4  ]) = (unsigned int)f2bf(v1.x) | ((unsigned int)f2bf(v1.y) << 16);
      *(unsigned int*)(&d1[i*4+2]) = (unsigned int)f2bf(v1.z) | ((unsigned int)f2bf(v1.w) << 16);
    }
  }
  __syncthreads();

  #pragma unroll
  for (int n=0;n<4;++n){
    int xcol = wc*64 + n*16 + r16;
    float fx = 0.5f*(float)xcol - 0.25f;
    int ixf = (int)floorf(fx);
    float tx = fx - (float)ixf;
    int ix0 = ixf < 0 ? 0 : ixf;
    int ix1 = (ixf+1) > 63 ? 63 : (ixf+1);
    float wx1 = tx, wx0 = 1.0f - tx;
    #pragma unroll
    for (int m=0;m<4;++m){
      #pragma unroll
      for (int j=0;j<4;++j){
        int olo = wr*64 + m*16 + g*4 + j;
        float v00 = bf2f(epi[olo*132 + ix0]);
        float v01 = bf2f(epi[olo*132 + ix1]);
        float v10 = bf2f(epi[olo*132 + 64 + ix0]);
        float v11 = bf2f(epi[olo*132 + 64 + ix1]);
        float up = wy0*(wx0*v00 + wx1*v01) + wy1*(wx0*v10 + wx1*v11);
        int o = o0 + olo;
        out[((size_t)(b*NC + o))*IMG + (size_t)y*NW + xcol] = acc[m][n][j] + up;
      }
    }
  }
}

// =====================================================================
extern "C" void kernel_launch(void* const* d_in, const int* in_sizes, int n_in,
                              void* d_out, int out_size, void* d_ws, size_t ws_size,
                              hipStream_t stream){
  (void)in_sizes; (void)n_in; (void)out_size; (void)ws_size;
  const float* xhigh = (const float*)d_in[0];
  const float* xlow  = (const float*)d_in[1];
  const float* w1    = (const float*)d_in[2];
  const float* b1    = (const float*)d_in[3];
  const float* w2    = (const float*)d_in[4];
  const float* b2    = (const float*)d_in[5];
  const float* rw    = (const float*)d_in[6];

  char* ws = (char*)d_ws;
  unsigned short* filt  = (unsigned short*)(ws);                    // 67,108,864
  unsigned short* filtT = (unsigned short*)(ws + 67108864);         // 67,108,864
  float* GH   = (float*)(ws + 134217728);                           // 26,214,400
  float* AB   = (float*)(ws + 160432128);                           // 25,165,824
  float* kern = (float*)(ws + 185597952);                           // 4,096 (pad)
  float* KL   = (float*)(ws + 185602048);                           // 114,688
  float* Wf   = (float*)(ws + 185716736);                           // 524,288
  unsigned short* rwbf = (unsigned short*)(ws + 186241024);         // 131,072

  K1   <<<NIMG, 512, 0, stream>>>(xlow, GH);
  K_mlp<<<NB,   64,  0, stream>>>(GH, w1, b1, w2, b2, kern);
  K3   <<<NB,   256, 0, stream>>>(kern, KL, Wf);
  K_w  <<<256,  256, 0, stream>>>(rw, rwbf);
  K_tab<<<NIMG, 128, 0, stream>>>(GH, KL, kern, AB);
  K4   <<<NIMG, 256, 0, stream>>>(xlow, Wf, AB, filt);
  K_trans<<<dim3(256, 4, NB), 256, 0, stream>>>(filt, filtT);
  K_gemm <<<dim3(256, 1, NB), 256, 0, stream>>>(rwbf, filtT, xhigh, (float*)d_out);
}

// Round 7
// 301.092 us; speedup vs baseline: 1.1344x; 1.1344x over previous
//
#include <hip/hip_runtime.h>

typedef __attribute__((ext_vector_type(8))) short bf16x8;
typedef __attribute__((ext_vector_type(4))) float f32x4;
typedef __attribute__((ext_vector_type(4))) int   i32x4;

#define PI_F 3.14159265358979323846f
#define C128 0.0490873852123405f      /* 2*pi/128 */
#define INV_SQRT128 0.0883883476483184f
#define INV128 0.0078125f

#define NB 8
#define NC 256
#define NH 128
#define NW 128
#define IMG 16384
#define NIMG 2048

// GH per-image layout (floats, stride 3200):
//  [0..1535]    G  : [w6][re/im][128]   (w = 61..66)
//  [1536..3071] Hh : [z6][re/im][128]   (z = 61..66)
//  [3072..3143] Fc : 36 complex (w6 x z6)
//  [3144..3192] magC: 49
#define GH_STRIDE 3200
// AB per-image layout (floats, stride 3072)
#define AB_STRIDE 3072

__device__ __forceinline__ unsigned short f2bf(float f){
  unsigned int u = __float_as_uint(f);
  u += 0x7FFFu + ((u >> 16) & 1u);
  return (unsigned short)(u >> 16);
}
__device__ __forceinline__ float bf2f(unsigned short u){
  return __uint_as_float(((unsigned int)u) << 16);
}

__device__ __constant__ int c_pcnt[6] = {1,2,3,3,2,1};
__device__ __constant__ int c_pdp0[6] = {6,5,4,0,0,0};

#define COS1 0.9987954562051724f
#define SIN1 0.0490676743274180f
#define K1CH (2.0f*COS1)

// LDS float offsets for K1 (total 10240 floats = 40960 B -> 4 blocks/CU)
#define SM_GG   8320     /* Gg [4][2][128] = 1024 floats */
#define SM_HLR  9344     /* HloR [4][128]  = 512 floats  */
#define SM_HLI  9856     /* HloI [3][128]  = 384 floats  */
#define SM_SCRG 1920     /* col scratch (aliases xs)     */

// =====================================================================
// K1: per image: high-freq partial DFTs G,Hh + corner Fc + magC(49).
// 512 threads: 256 row-DFT (half-row each), 256 col-DFT (half-col each).
// (round-5 proven version)
// =====================================================================
__global__ void __launch_bounds__(512, 8) K1(const float* __restrict__ xlow,
                                             float* __restrict__ GH){
  __shared__ float smem[10240];
  unsigned short* xs = (unsigned short*)smem;   // stride 130 u16
  const int tid = threadIdx.x;
  const int img = blockIdx.x;
  float* ghb = GH + (size_t)img*GH_STRIDE;

  // ---- stage x -> bf16 LDS ----
  {
    const float4* xp = (const float4*)(xlow + (size_t)img*IMG);
    #pragma unroll
    for (int k=0; k<8; ++k){
      int e4 = k*512 + tid;
      float4 v = xp[e4];
      int r = e4 >> 5, c = (e4 & 31)*4;
      unsigned int pw0 = (unsigned int)f2bf(v.x) | ((unsigned int)f2bf(v.y) << 16);
      unsigned int pw1 = (unsigned int)f2bf(v.z) | ((unsigned int)f2bf(v.w) << 16);
      *(unsigned int*)(&xs[r*130 + c    ]) = pw0;
      *(unsigned int*)(&xs[r*130 + c + 2]) = pw1;
    }
  }
  __syncthreads();

  float acc[14];
  #pragma unroll
  for (int i=0;i<14;++i) acc[i]=0.f;

  const int isRow = (tid < 256);
  const int lid  = isRow ? tid : (tid-256);
  const int idx  = lid & 127;
  const int half = lid >> 7;

  {
    const float sg0 = half ? -1.f : 1.f;
    float cp = sg0, sp = 0.f;
    float cn = sg0*COS1, sn = sg0*SIN1;

#define K1_ACCUM(xv, cc, ss)                                   \
    {                                                          \
      float t2 = cc + cc;                                      \
      float c2 = fmaf(t2, cc, -1.f);                           \
      float s2 = t2 * ss;                                      \
      float c3 = fmaf(t2, c2, -cc);                            \
      float s3 = fmaf(t2, s2, -ss);                            \
      acc[0 + PARITY] += xv;                                   \
      acc[2 + PARITY*2]  = fmaf(xv, cc, acc[2 + PARITY*2]);    \
      acc[3 + PARITY*2]  = fmaf(xv, ss, acc[3 + PARITY*2]);    \
      acc[6 + PARITY*2]  = fmaf(xv, c2, acc[6 + PARITY*2]);    \
      acc[7 + PARITY*2]  = fmaf(xv, s2, acc[7 + PARITY*2]);    \
      acc[10 + PARITY*2] = fmaf(xv, c3, acc[10 + PARITY*2]);   \
      acc[11 + PARITY*2] = fmaf(xv, s3, acc[11 + PARITY*2]);   \
    }

    if (isRow){
      const unsigned short* xr = &xs[idx*130 + half*64];
      #pragma unroll 4
      for (int j=0; j<32; ++j){
        unsigned int pk = *(const unsigned int*)(&xr[2*j]);
        float xe = __uint_as_float(pk << 16);
        float xo = __uint_as_float(pk & 0xffff0000u);
#define PARITY 0
        K1_ACCUM(xe, cp, sp)
#undef PARITY
#define PARITY 1
        K1_ACCUM(xo, cn, sn)
#undef PARITY
        float cpn = fmaf(K1CH, cn, -cp);
        float spn = fmaf(K1CH, sn, -sp);
        float cnn = fmaf(K1CH, cpn, -cn);
        float snn = fmaf(K1CH, spn, -sn);
        cp = cpn; sp = spn; cn = cnn; sn = snn;
      }
    } else {
      const unsigned short* xc = &xs[half*64*130 + idx];
      #pragma unroll 4
      for (int j=0; j<32; ++j){
        float xe = bf2f(xc[(2*j  )*130]);
        float xo = bf2f(xc[(2*j+1)*130]);
#define PARITY 0
        K1_ACCUM(xe, cp, sp)
#undef PARITY
#define PARITY 1
        K1_ACCUM(xo, cn, sn)
#undef PARITY
        float cpn = fmaf(K1CH, cn, -cp);
        float spn = fmaf(K1CH, sn, -sp);
        float cnn = fmaf(K1CH, cpn, -cn);
        float snn = fmaf(K1CH, spn, -sn);
        cp = cpn; sp = spn; cn = cnn; sn = snn;
      }
    }
#undef K1_ACCUM
  }
  __syncthreads();     // xs reads done; scratch may overwrite

  const int scrbase = (isRow ? 0 : SM_SCRG) + idx*15;
  if (half){
    #pragma unroll
    for (int i=0;i<14;++i) smem[scrbase+i] = acc[i];
  }
  __syncthreads();
  if (!half){
    #pragma unroll
    for (int i=0;i<14;++i) acc[i] += smem[scrbase+i];
    float A0e=acc[0],A0o=acc[1],Ce1=acc[2],Se1=acc[3],Co1=acc[4],So1=acc[5],
          Ce2=acc[6],Se2=acc[7],Co2=acc[8],So2=acc[9],
          Ce3=acc[10],Se3=acc[11],Co3=acc[12],So3=acc[13];
    float d0  = A0e-A0o;
    float dc1 = Ce1-Co1, ds1 = Se1-So1;
    float dc2 = Ce2-Co2, ds2 = Se2-So2;
    float dc3 = Ce3-Co3, ds3 = Se3-So3;
    float* gp = ghb + (isRow ? 1536 : 0);
    const int k = idx;
    gp[(0*2+0)*128+k] = dc3*INV_SQRT128;  gp[(0*2+1)*128+k] =  ds3*INV_SQRT128;
    gp[(1*2+0)*128+k] = dc2*INV_SQRT128;  gp[(1*2+1)*128+k] =  ds2*INV_SQRT128;
    gp[(2*2+0)*128+k] = dc1*INV_SQRT128;  gp[(2*2+1)*128+k] =  ds1*INV_SQRT128;
    gp[(3*2+0)*128+k] = d0 *INV_SQRT128;  gp[(3*2+1)*128+k] =  0.f;
    gp[(4*2+0)*128+k] = dc1*INV_SQRT128;  gp[(4*2+1)*128+k] = -ds1*INV_SQRT128;
    gp[(5*2+0)*128+k] = dc2*INV_SQRT128;  gp[(5*2+1)*128+k] = -ds2*INV_SQRT128;
    if (isRow){
      smem[SM_HLR + 0*128 + k] = A0e+A0o;
      smem[SM_HLR + 1*128 + k] = Ce1+Co1;
      smem[SM_HLR + 2*128 + k] = Ce2+Co2;
      smem[SM_HLR + 3*128 + k] = Ce3+Co3;
      smem[SM_HLI + 0*128 + k] = -(Se1+So1);
      smem[SM_HLI + 1*128 + k] = -(Se2+So2);
      smem[SM_HLI + 2*128 + k] = -(Se3+So3);
    } else {
      smem[SM_GG + (0*2+0)*128 + k] = dc3;  smem[SM_GG + (0*2+1)*128 + k] = ds3;
      smem[SM_GG + (1*2+0)*128 + k] = dc2;  smem[SM_GG + (1*2+1)*128 + k] = ds2;
      smem[SM_GG + (2*2+0)*128 + k] = dc1;  smem[SM_GG + (2*2+1)*128 + k] = ds1;
      smem[SM_GG + (3*2+0)*128 + k] = d0;   smem[SM_GG + (3*2+1)*128 + k] = 0.f;
    }
  }
  __syncthreads();

  // ---- Fc tail: 36 outputs x 4 chunks ----
  if (tid < 144){
    int out = tid >> 2, chunk = tid & 3;
    int wi = out/6, zi = out%6, z = 61+zi;
    int wsrc = (wi<4) ? wi : (wi==4 ? 2 : 1);
    float isg = (wi<4) ? 1.f : -1.f;
    float fR=0.f, fI=0.f;
    const int cEnd = chunk*32 + 32;
    for (int c=chunk*32; c<cEnd; ++c){
      float gR = smem[SM_GG + (wsrc*2  )*128 + c];
      float gI = isg*smem[SM_GG + (wsrc*2+1)*128 + c];
      int m = (z*c) & 127;
      float ts, tc; __sincosf((float)m*C128, &ts, &tc);
      fR += gR*tc + gI*ts;
      fI += gI*tc - gR*ts;
    }
    fR += __shfl_xor(fR,1); fI += __shfl_xor(fI,1);
    fR += __shfl_xor(fR,2); fI += __shfl_xor(fI,2);
    if (chunk==0){
      ghb[3072 + out*2]     = fR * INV128;
      ghb[3072 + out*2 + 1] = fI * INV128;
    }
  }
  // ---- magC tail: 49 outputs x 4 chunks ----
  if (tid >= 256 && tid < 452){
    int i = (tid-256) >> 2, chunk = (tid-256) & 3;
    int u = i/7 - 3, v = i%7 - 3;
    int va = v < 0 ? -v : v;
    float vsg = v < 0 ? -1.f : 1.f;
    float fR=0.f, fI=0.f;
    const int rEnd = chunk*32 + 32;
    for (int r=chunk*32; r<rEnd; ++r){
      float hR = smem[SM_HLR + va*128 + r];
      float hI = (va==0) ? 0.f : vsg*smem[SM_HLI + (va-1)*128 + r];
      int m = ((u*r) % 128 + 128) & 127;
      float ts, tc; __sincosf((float)m*C128, &ts, &tc);
      fR += hR*tc + hI*ts;
      fI += hI*tc - hR*ts;
    }
    fR += __shfl_xor(fR,1); fI += __shfl_xor(fI,1);
    fR += __shfl_xor(fR,2); fI += __shfl_xor(fI,2);
    if (chunk==0){
      fR *= INV128; fI *= INV128;
      ghb[3144 + i] = sqrtf(fR*fR + fI*fI);
    }
  }
}

// =====================================================================
// K_mlp
// =====================================================================
__global__ void __launch_bounds__(64) K_mlp(const float* __restrict__ GH,
                                            const float* __restrict__ w1,
                                            const float* __restrict__ b1,
                                            const float* __restrict__ w2,
                                            const float* __restrict__ b2,
                                            float* __restrict__ kern){
  __shared__ float flat[49];
  __shared__ float hh[32];
  const int b = blockIdx.x, tid = threadIdx.x;
  if (tid < 49){
    float s = 0.f;
    for (int c=0; c<256; ++c)
      s += GH[(size_t)(b*256 + c)*GH_STRIDE + 3144 + tid];
    flat[tid] = s * (1.0f/256.0f);
  }
  __syncthreads();
  if (tid < 32){
    float s = b1[tid];
    for (int i=0; i<49; ++i) s += flat[i]*w1[tid*49+i];
    hh[tid] = fmaxf(s, 0.f);
  }
  __syncthreads();
  if (tid == 0){
    float p[3];
    #pragma unroll
    for (int k=0; k<3; ++k){
      float s = b2[k];
      for (int j=0; j<32; ++j) s += hh[j]*w2[k*32+j];
      p[k] = s;
    }
    float theta = atan2f(p[0], p[1])*0.5f + 1.57079632679489662f;
    float ct = cosf(theta), st = sinf(theta);
    float l1 = expf(p[2]);
    float l2 = 1.0f/(l1 + 1e-8f);
    float inv1 = 1.0f/(2.0f*l1*l1);
    float inv2 = 1.0f/(2.0f*l2*l2);
    float sum = 0.f;
    for (int i=0; i<7; ++i) for (int j=0; j<7; ++j){
      float yy = (float)(i-3), xx = (float)(j-3);
      float xr =  xx*ct + yy*st;
      float yr = -xx*st + yy*ct;
      sum += expf(-(xr*xr*inv1 + yr*yr*inv2));
    }
    float inv = 1.0f/(sum + 1e-8f);
    for (int i=0; i<7; ++i) for (int j=0; j<7; ++j){
      float yy = (float)(i-3), xx = (float)(j-3);
      float xr =  xx*ct + yy*st;
      float yr = -xx*st + yy*ct;
      kern[b*49 + i*7 + j] = expf(-(xr*xr*inv1 + yr*yr*inv2)) * inv;
    }
  }
}

// =====================================================================
// K3: per batch: kappa/lambda tables + W field
// =====================================================================
__global__ void __launch_bounds__(256) K3(const float* __restrict__ kern,
                                          float* __restrict__ KL,
                                          float* __restrict__ W){
  __shared__ float twc[128], tws[128], kl[49];
  __shared__ float kapl[7][2][128];
  const int b = blockIdx.x, tid = threadIdx.x;
  if (tid < 128){
    float s,c; __sincosf((float)tid*C128, &s, &c);
    twc[tid]=c; tws[tid]=s;
  }
  if (tid < 49) kl[tid] = kern[b*49 + tid];
  __syncthreads();
  if (tid < 128){
    const int c = tid;
    float* klb = KL + (size_t)b*3584;
    #pragma unroll
    for (int dp=0; dp<7; ++dp){
      float kR=0.f, kI=0.f;
      #pragma unroll
      for (int dq=0; dq<7; ++dq){
        int m = (((dq-3)*c) % 128 + 128) & 127;
        float kv = kl[dp*7+dq];
        kR += kv*twc[m]; kI -= kv*tws[m];
      }
      klb[(dp*2  )*128 + c] = kR;
      klb[(dp*2+1)*128 + c] = kI;
      kapl[dp][0][c] = kR; kapl[dp][1][c] = kI;
    }
    const int r = tid;
    #pragma unroll
    for (int dq=0; dq<7; ++dq){
      float lR=0.f, lI=0.f;
      #pragma unroll
      for (int dp=0; dp<7; ++dp){
        int m = (((dp-3)*r) % 128 + 128) & 127;
        float kv = kl[dp*7+dq];
        lR += kv*twc[m]; lI -= kv*tws[m];
      }
      klb[1792 + (dq*2  )*128 + r] = lR;
      klb[1792 + (dq*2+1)*128 + r] = lI;
    }
  }
  __syncthreads();
  for (int k=0;k<64;++k){
    int px = k*256 + tid;
    int r = px >> 7, c = px & 127;
    float w = 0.f;
    #pragma unroll
    for (int dp=0; dp<7; ++dp){
      int m = (((dp-3)*r) % 128 + 128) & 127;
      w += twc[m]*kapl[dp][0][c] + tws[m]*kapl[dp][1][c];
    }
    W[(size_t)b*IMG + px] = w;
  }
}

// =====================================================================
// K_tab: per image: Abar (corner-folded) and Bbar tables
// =====================================================================
__global__ void __launch_bounds__(128) K_tab(const float* __restrict__ GH,
                                             const float* __restrict__ KL,
                                             const float* __restrict__ kern,
                                             float* __restrict__ AB){
  __shared__ float dRe[36], dIm[36], kl[49];
  const int tid = threadIdx.x;
  const int img = blockIdx.x, b = img >> 8;
  const float* ghb = GH + (size_t)img*GH_STRIDE;
  const float* klb = KL + (size_t)b*3584;
  float* abb = AB + (size_t)img*AB_STRIDE;

  if (tid < 49) kl[tid] = kern[b*49 + tid];
  __syncthreads();
  if (tid < 36){
    int si = tid/6, ti = tid%6;
    float dR=0.f, dI=0.f;
    for (int j=0; j<c_pcnt[si]; ++j){
      int dp = c_pdp0[si] + j;
      int wi = (si-3) + dp;
      for (int l=0; l<c_pcnt[ti]; ++l){
        int dq = c_pdp0[ti] + l;
        int zi = (ti-3) + dq;
        float kv = kl[dp*7+dq];
        dR += kv * ghb[3072 + (wi*6+zi)*2];
        dI += kv * ghb[3072 + (wi*6+zi)*2 + 1];
      }
    }
    dRe[tid] = dR; dIm[tid] = dI;
  }
  __syncthreads();

  const int c = tid;
  float s1,c1; __sincosf((float)c*C128, &s1, &c1);
  float c2 = c1*c1 - s1*s1, s2 = 2.f*c1*s1;
  float c3 = c1*c2 - s1*s2, s3 = s1*c2 + c1*s2;
  float ct[6] = {c3,c2,c1,1.f,c1,c2};
  float st[6] = {-s3,-s2,-s1,0.f,s1,s2};
  float sgnc = (c & 1) ? -1.f : 1.f;

  float gr[6], gi[6], kr[7], ki[7];
  #pragma unroll
  for (int w=0;w<6;++w){ gr[w]=ghb[(w*2)*128+c]; gi[w]=ghb[(w*2+1)*128+c]; }
  #pragma unroll
  for (int dp=0;dp<7;++dp){ kr[dp]=klb[(dp*2)*128+c]; ki[dp]=klb[(dp*2+1)*128+c]; }

  #pragma unroll
  for (int si=0; si<6; ++si){
    float dR=0.f, dI=0.f;
    for (int j=0; j<c_pcnt[si]; ++j){
      int dp = c_pdp0[si] + j;
      int w = (si-3) + dp;
      dR += kr[dp]*gr[w] - ki[dp]*gi[w];
      dI += kr[dp]*gi[w] + ki[dp]*gr[w];
    }
    float corrR=0.f, corrI=0.f;
    #pragma unroll
    for (int ti=0; ti<6; ++ti){
      float DR = dRe[si*6+ti], DI = dIm[si*6+ti];
      corrR += DR*ct[ti] - DI*st[ti];
      corrI += DR*st[ti] + DI*ct[ti];
    }
    abb[(si*2  )*128 + c] = INV_SQRT128*dR - INV128*sgnc*corrR;
    abb[(si*2+1)*128 + c] = INV_SQRT128*dI - INV128*sgnc*corrI;
  }

  const int r = tid;
  float hr[6], hi_[6], lr[7], li[7];
  #pragma unroll
  for (int z=0;z<6;++z){ hr[z]=ghb[1536+(z*2)*128+r]; hi_[z]=ghb[1536+(z*2+1)*128+r]; }
  #pragma unroll
  for (int dq=0;dq<7;++dq){ lr[dq]=klb[1792+(dq*2)*128+r]; li[dq]=klb[1792+(dq*2+1)*128+r]; }
  #pragma unroll
  for (int ti=0; ti<6; ++ti){
    float bR=0.f, bI=0.f;
    for (int l=0; l<c_pcnt[ti]; ++l){
      int dq = c_pdp0[ti] + l;
      int z = (ti-3) + dq;
      bR += lr[dq]*hr[z] - li[dq]*hi_[z];
      bI += lr[dq]*hi_[z] + li[dq]*hr[z];
    }
    abb[1536 + r*12 + ti*2]     = INV_SQRT128*bR;
    abb[1536 + r*12 + ti*2 + 1] = INV_SQRT128*bI;
  }
}

// =====================================================================
// K4: per image: filt = x*W - E  (bf16 out), float2 per lane
// =====================================================================
__global__ void __launch_bounds__(256) K4(const float* __restrict__ xlow,
                                          const float* __restrict__ W,
                                          const float* __restrict__ AB,
                                          unsigned short* __restrict__ filt){
  const int tid = threadIdx.x;
  const int img = blockIdx.x, b = img >> 8;
  const int c0 = (tid & 63)*2, grp = tid >> 6;
  const float* abb = AB + (size_t)img*AB_STRIDE;
  const float* xim = xlow + (size_t)img*IMG;
  const float* Wb  = W + (size_t)b*IMG;
  unsigned short* fim = filt + (size_t)img*IMG;

  float ar[2][6], ai[2][6], ctc[2][6], stc[2][6];
  #pragma unroll
  for (int col=0; col<2; ++col){
    int c = c0 + col;
    #pragma unroll
    for (int si=0;si<6;++si){ ar[col][si]=abb[(si*2)*128+c]; ai[col][si]=abb[(si*2+1)*128+c]; }
    float s1,c1; __sincosf((float)c*C128, &s1, &c1);
    float c2 = c1*c1 - s1*s1, s2 = 2.f*c1*s1;
    float c3 = c1*c2 - s1*s2, s3 = s1*c2 + c1*s2;
    ctc[col][0]=c3; ctc[col][1]=c2; ctc[col][2]=c1; ctc[col][3]=1.f; ctc[col][4]=c1; ctc[col][5]=c2;
    stc[col][0]=-s3; stc[col][1]=-s2; stc[col][2]=-s1; stc[col][3]=0.f; stc[col][4]=s1; stc[col][5]=s2;
  }

  for (int k=0;k<32;++k){
    int ru = __builtin_amdgcn_readfirstlane(grp*32 + k);
    const float* brow = abb + 1536 + ru*12;
    float4 b0 = *(const float4*)(brow);
    float4 b1 = *(const float4*)(brow+4);
    float4 b2 = *(const float4*)(brow+8);
    float rs1,rc1; __sincosf((float)ru*C128, &rs1, &rc1);
    float rc2 = rc1*rc1 - rs1*rs1, rs2 = 2.f*rc1*rs1;
    float rc3 = rc1*rc2 - rs1*rs2, rs3 = rs1*rc2 + rc1*rs2;
    float rcs[6] = {rc3,rc2,rc1,1.f,rc1,rc2};
    float rss[6] = {-rs3,-rs2,-rs1,0.f,rs1,rs2};

    float ER0 = 0.f, ER1 = 0.f;
    #pragma unroll
    for (int si=0;si<6;++si){
      ER0 += rcs[si]*ar[0][si] - rss[si]*ai[0][si];
      ER1 += rcs[si]*ar[1][si] - rss[si]*ai[1][si];
    }
    float rsg = (ru & 1) ? -1.f : 1.f;
    ER0 *= rsg; ER1 *= rsg;

    float bRv[6] = {b0.x, b0.z, b1.x, b1.z, b2.x, b2.z};
    float bIv[6] = {b0.y, b0.w, b1.y, b1.w, b2.y, b2.w};
    float EC0 = 0.f, EC1 = 0.f;
    #pragma unroll
    for (int ti=0;ti<6;++ti){
      EC0 += ctc[0][ti]*bRv[ti] - stc[0][ti]*bIv[ti];
      EC1 += ctc[1][ti]*bRv[ti] - stc[1][ti]*bIv[ti];
    }
    int px = ru*128 + c0;
    float2 xv = *(const float2*)(&xim[px]);
    float2 wv = *(const float2*)(&Wb[px]);
    float v0 = xv.x*wv.x - ER0 - EC0;
    float v1 = xv.y*wv.y - ER1 + EC1;
    unsigned int pack = ((unsigned int)f2bf(v1) << 16) | (unsigned int)f2bf(v0);
    *(unsigned int*)(&fim[px]) = pack;
  }
}

// =====================================================================
// K_w: refine_w f32 -> bf16
// =====================================================================
__global__ void __launch_bounds__(256) K_w(const float* __restrict__ rw,
                                           unsigned short* __restrict__ rwbf){
  int i = blockIdx.x*256 + threadIdx.x;
  rwbf[i] = f2bf(rw[i]);
}

// =====================================================================
// K_up: bilinear upsample x_high (64x64 -> 128x128) as bf16
// =====================================================================
__global__ void __launch_bounds__(256) K_up(const float* __restrict__ xhigh,
                                            unsigned short* __restrict__ up){
  __shared__ float xs[64*68];
  const int tid = threadIdx.x;
  const int img = blockIdx.x;
  const float* src = xhigh + (size_t)img*4096;
  unsigned short* dst = up + (size_t)img*IMG;

  #pragma unroll
  for (int p=0; p<4; ++p){
    int t = p*256 + tid;
    float4 v = ((const float4*)src)[t];
    int r = t >> 4, k = t & 15;
    *(float4*)(&xs[r*68 + k*4]) = v;
  }
  __syncthreads();

  for (int k=0; k<32; ++k){
    int pr = k*256 + tid;
    int y = pr >> 6, x0 = (pr & 63)*2;
    float fy = 0.5f*(float)y - 0.25f;
    int iyf = (int)floorf(fy);
    float ty = fy - (float)iyf;
    int iy0 = iyf < 0 ? 0 : iyf;
    int iy1 = (iyf+1) > 63 ? 63 : (iyf+1);
    float wy1 = ty, wy0 = 1.0f - ty;
    const float* r0 = &xs[iy0*68];
    const float* r1 = &xs[iy1*68];

    float outv[2];
    #pragma unroll
    for (int e=0; e<2; ++e){
      int x = x0 + e;
      float fx = 0.5f*(float)x - 0.25f;
      int ixf = (int)floorf(fx);
      float tx = fx - (float)ixf;
      int ix0 = ixf < 0 ? 0 : ixf;
      int ix1 = (ixf+1) > 63 ? 63 : (ixf+1);
      float wx1 = tx, wx0 = 1.0f - tx;
      outv[e] = wy0*(wx0*r0[ix0] + wx1*r0[ix1])
              + wy1*(wx0*r1[ix0] + wx1*r1[ix1]);
    }
    unsigned int pack = ((unsigned int)f2bf(outv[1]) << 16) | (unsigned int)f2bf(outv[0]);
    *(unsigned int*)(&dst[y*NW + x0]) = pack;
  }
}

// =====================================================================
// K_gemm: out[b,o,p] = sum_c rw[o,c]*filt[b,c,p] + up[b,o,p]
// Fused transpose: B staged from filt[b][c][p] directly, transposed in
// registers (u16-pair -> u32) into Bt[p][c] (stride 40 u16, 16B-aligned,
// bank-spread). Double-buffered LDS, 1 barrier per K-step. XCD-paired
// grid so the two o-tiles of one p-tile share filt reads via L2.
// =====================================================================
__global__ void __launch_bounds__(256) K_gemm(const unsigned short* __restrict__ rwbf,
                                              const unsigned short* __restrict__ filt,
                                              const unsigned short* __restrict__ up,
                                              float* __restrict__ out){
  __shared__ unsigned short At[2][128*40];
  __shared__ unsigned short Bt[2][128*40];
  const int tid = threadIdx.x, lane = tid & 63, wv = tid >> 6;
  const int wr = wv >> 1, wc = wv & 1;
  const int xg = blockIdx.x;
  const int g16 = xg >> 4, i16 = xg & 15;
  const int ot = i16 >> 3, pt = (g16 << 3) | (i16 & 7);
  const int b = blockIdx.z;
  const int p0 = pt*128, o0 = ot*128;

  f32x4 acc[4][4];
  #pragma unroll
  for (int m=0;m<4;++m)
    #pragma unroll
    for (int n=0;n<4;++n){ f32x4 z = {0.f,0.f,0.f,0.f}; acc[m][n] = z; }

  // A staging: rwbf[o][c] row-major, k-contiguous
  const int arow  = tid >> 2;          // 0..63
  const int akoff = (tid & 3) * 8;     // u16 offset, 0..24
  const unsigned short* aP0 = &rwbf[(size_t)(o0+arow   )*256 + akoff];
  const unsigned short* aP1 = &rwbf[(size_t)(o0+arow+64)*256 + akoff];

  // B staging: filt[b][c][p]; thread loads channel pair (bc2, bc2+1),
  // 8 p's, repacks to transposed u32 writes.
  const int bc2 = (tid & 15) * 2;      // 0..30 (even channel in k-tile)
  const int bpo = (tid >> 4) * 8;      // p offset within tile, 0..120
  const unsigned short* bP0 = &filt[((size_t)b*NC + bc2    )*IMG + p0 + bpo];
  const unsigned short* bP1 = &filt[((size_t)b*NC + bc2 + 1)*IMG + p0 + bpo];

  i32x4 av0 = *(const i32x4*)(aP0);
  i32x4 av1 = *(const i32x4*)(aP1);
  i32x4 bv0 = *(const i32x4*)(bP0);
  i32x4 bv1 = *(const i32x4*)(bP1);

#define BT_STORE(BUF)                                                        \
  {                                                                          \
    _Pragma("unroll")                                                        \
    for (int j=0;j<4;++j){                                                   \
      unsigned int w0 = (unsigned int)bv0[j];                                \
      unsigned int w1 = (unsigned int)bv1[j];                                \
      unsigned int lo = (w0 & 0xffffu) | (w1 << 16);                         \
      unsigned int hi = (w0 >> 16) | (w1 & 0xffff0000u);                     \
      *(unsigned int*)(&Bt[BUF][(bpo+2*j  )*40 + bc2]) = lo;                 \
      *(unsigned int*)(&Bt[BUF][(bpo+2*j+1)*40 + bc2]) = hi;                 \
    }                                                                        \
  }

  *(i32x4*)(&At[0][ arow    *40 + akoff]) = av0;
  *(i32x4*)(&At[0][(arow+64)*40 + akoff]) = av1;
  BT_STORE(0)
  __syncthreads();

  const int g = lane >> 4, r16 = lane & 15;
  for (int ks=0; ks<8; ++ks){
    const int cur = ks & 1;
    if (ks < 7){
      const int ka = (ks+1)*32;
      av0 = *(const i32x4*)(aP0 + ka);
      av1 = *(const i32x4*)(aP1 + ka);
      bv0 = *(const i32x4*)(bP0 + (size_t)(ks+1)*32*IMG);
      bv1 = *(const i32x4*)(bP1 + (size_t)(ks+1)*32*IMG);
    }
    bf16x8 af[4], bfr[4];
    #pragma unroll
    for (int m=0;m<4;++m) af[m]  = *(const bf16x8*)(&At[cur][(wr*64 + m*16 + r16)*40 + g*8]);
    #pragma unroll
    for (int n=0;n<4;++n) bfr[n] = *(const bf16x8*)(&Bt[cur][(wc*64 + n*16 + r16)*40 + g*8]);
    #pragma unroll
    for (int m=0;m<4;++m)
      #pragma unroll
      for (int n=0;n<4;++n)
        acc[m][n] = __builtin_amdgcn_mfma_f32_16x16x32_bf16(af[m], bfr[n], acc[m][n], 0, 0, 0);
    if (ks < 7){
      const int nxt = cur ^ 1;
      *(i32x4*)(&At[nxt][ arow    *40 + akoff]) = av0;
      *(i32x4*)(&At[nxt][(arow+64)*40 + akoff]) = av1;
      if (nxt) BT_STORE(1) else BT_STORE(0)
      __syncthreads();
    }
  }
#undef BT_STORE

  // epilogue: out = acc + up (same-address coalesced load/store)
  const int y = pt;
  #pragma unroll
  for (int m=0;m<4;++m){
    #pragma unroll
    for (int j=0;j<4;++j){
      int o = o0 + wr*64 + m*16 + g*4 + j;
      size_t base = (size_t)(b*NC + o)*IMG + (size_t)y*NW;
      #pragma unroll
      for (int n=0;n<4;++n){
        int xcol = wc*64 + n*16 + r16;
        float upv = bf2f(up[base + xcol]);
        out[base + xcol] = acc[m][n][j] + upv;
      }
    }
  }
}

// =====================================================================
extern "C" void kernel_launch(void* const* d_in, const int* in_sizes, int n_in,
                              void* d_out, int out_size, void* d_ws, size_t ws_size,
                              hipStream_t stream){
  (void)in_sizes; (void)n_in; (void)out_size; (void)ws_size;
  const float* xhigh = (const float*)d_in[0];
  const float* xlow  = (const float*)d_in[1];
  const float* w1    = (const float*)d_in[2];
  const float* b1    = (const float*)d_in[3];
  const float* w2    = (const float*)d_in[4];
  const float* b2    = (const float*)d_in[5];
  const float* rw    = (const float*)d_in[6];

  char* ws = (char*)d_ws;
  unsigned short* filt  = (unsigned short*)(ws);                    // 67,108,864
  unsigned short* up    = (unsigned short*)(ws + 67108864);         // 67,108,864 (old filtT slot)
  float* GH   = (float*)(ws + 134217728);                           // 26,214,400
  float* AB   = (float*)(ws + 160432128);                           // 25,165,824
  float* kern = (float*)(ws + 185597952);                           // 4,096 (pad)
  float* KL   = (float*)(ws + 185602048);                           // 114,688
  float* Wf   = (float*)(ws + 185716736);                           // 524,288
  unsigned short* rwbf = (unsigned short*)(ws + 186241024);         // 131,072

  K1   <<<NIMG, 512, 0, stream>>>(xlow, GH);
  K_mlp<<<NB,   64,  0, stream>>>(GH, w1, b1, w2, b2, kern);
  K3   <<<NB,   256, 0, stream>>>(kern, KL, Wf);
  K_w  <<<256,  256, 0, stream>>>(rw, rwbf);
  K_tab<<<NIMG, 128, 0, stream>>>(GH, KL, kern, AB);
  K4   <<<NIMG, 256, 0, stream>>>(xlow, Wf, AB, filt);
  K_up <<<NIMG, 256, 0, stream>>>(xhigh, up);
  K_gemm <<<dim3(256, 1, NB), 256, 0, stream>>>(rwbf, filt, up, (float*)d_out);
}

// Round 8
// 286.429 us; speedup vs baseline: 1.1925x; 1.0512x over previous
//
#include <hip/hip_runtime.h>

typedef __attribute__((ext_vector_type(8))) short bf16x8;
typedef __attribute__((ext_vector_type(4))) float f32x4;
typedef __attribute__((ext_vector_type(4))) int   i32x4;

#define PI_F 3.14159265358979323846f
#define C128 0.0490873852123405f      /* 2*pi/128 */
#define INV_SQRT128 0.0883883476483184f
#define INV128 0.0078125f

#define NB 8
#define NC 256
#define NH 128
#define NW 128
#define IMG 16384
#define NIMG 2048

// GH per-image layout (floats, stride 3200):
//  [0..1535]    G  : [w6][re/im][128]   (w = 61..66)
//  [1536..3071] Hh : [z6][re/im][128]   (z = 61..66)
//  [3072..3143] Fc : 36 complex (w6 x z6)
//  [3144..3192] magC: 49
#define GH_STRIDE 3200
// AB per-image layout (floats, stride 3072)
#define AB_STRIDE 3072

__device__ __forceinline__ unsigned short f2bf(float f){
  unsigned int u = __float_as_uint(f);
  u += 0x7FFFu + ((u >> 16) & 1u);
  return (unsigned short)(u >> 16);
}
__device__ __forceinline__ float bf2f(unsigned short u){
  return __uint_as_float(((unsigned int)u) << 16);
}

__device__ __constant__ int c_pcnt[6] = {1,2,3,3,2,1};
__device__ __constant__ int c_pdp0[6] = {6,5,4,0,0,0};

#define COS1 0.9987954562051724f
#define SIN1 0.0490676743274180f
#define K1CH (2.0f*COS1)

// LDS float offsets for K1 (total 10240 floats = 40960 B -> 4 blocks/CU)
#define SM_GG   8320     /* Gg [4][2][128] = 1024 floats */
#define SM_HLR  9344     /* HloR [4][128]  = 512 floats  */
#define SM_HLI  9856     /* HloI [3][128]  = 384 floats  */
#define SM_SCRG 1920     /* col scratch (aliases xs)     */

// =====================================================================
// K1: per image: high-freq partial DFTs G,Hh + corner Fc + magC(49).
// 512 threads: 256 row-DFT (half-row each), 256 col-DFT (half-col each).
// (round-5 proven version)
// =====================================================================
__global__ void __launch_bounds__(512, 8) K1(const float* __restrict__ xlow,
                                             float* __restrict__ GH){
  __shared__ float smem[10240];
  unsigned short* xs = (unsigned short*)smem;   // stride 130 u16
  const int tid = threadIdx.x;
  const int img = blockIdx.x;
  float* ghb = GH + (size_t)img*GH_STRIDE;

  // ---- stage x -> bf16 LDS ----
  {
    const float4* xp = (const float4*)(xlow + (size_t)img*IMG);
    #pragma unroll
    for (int k=0; k<8; ++k){
      int e4 = k*512 + tid;
      float4 v = xp[e4];
      int r = e4 >> 5, c = (e4 & 31)*4;
      unsigned int pw0 = (unsigned int)f2bf(v.x) | ((unsigned int)f2bf(v.y) << 16);
      unsigned int pw1 = (unsigned int)f2bf(v.z) | ((unsigned int)f2bf(v.w) << 16);
      *(unsigned int*)(&xs[r*130 + c    ]) = pw0;
      *(unsigned int*)(&xs[r*130 + c + 2]) = pw1;
    }
  }
  __syncthreads();

  float acc[14];
  #pragma unroll
  for (int i=0;i<14;++i) acc[i]=0.f;

  const int isRow = (tid < 256);
  const int lid  = isRow ? tid : (tid-256);
  const int idx  = lid & 127;
  const int half = lid >> 7;

  {
    const float sg0 = half ? -1.f : 1.f;
    float cp = sg0, sp = 0.f;
    float cn = sg0*COS1, sn = sg0*SIN1;

#define K1_ACCUM(xv, cc, ss)                                   \
    {                                                          \
      float t2 = cc + cc;                                      \
      float c2 = fmaf(t2, cc, -1.f);                           \
      float s2 = t2 * ss;                                      \
      float c3 = fmaf(t2, c2, -cc);                            \
      float s3 = fmaf(t2, s2, -ss);                            \
      acc[0 + PARITY] += xv;                                   \
      acc[2 + PARITY*2]  = fmaf(xv, cc, acc[2 + PARITY*2]);    \
      acc[3 + PARITY*2]  = fmaf(xv, ss, acc[3 + PARITY*2]);    \
      acc[6 + PARITY*2]  = fmaf(xv, c2, acc[6 + PARITY*2]);    \
      acc[7 + PARITY*2]  = fmaf(xv, s2, acc[7 + PARITY*2]);    \
      acc[10 + PARITY*2] = fmaf(xv, c3, acc[10 + PARITY*2]);   \
      acc[11 + PARITY*2] = fmaf(xv, s3, acc[11 + PARITY*2]);   \
    }

    if (isRow){
      const unsigned short* xr = &xs[idx*130 + half*64];
      #pragma unroll 4
      for (int j=0; j<32; ++j){
        unsigned int pk = *(const unsigned int*)(&xr[2*j]);
        float xe = __uint_as_float(pk << 16);
        float xo = __uint_as_float(pk & 0xffff0000u);
#define PARITY 0
        K1_ACCUM(xe, cp, sp)
#undef PARITY
#define PARITY 1
        K1_ACCUM(xo, cn, sn)
#undef PARITY
        float cpn = fmaf(K1CH, cn, -cp);
        float spn = fmaf(K1CH, sn, -sp);
        float cnn = fmaf(K1CH, cpn, -cn);
        float snn = fmaf(K1CH, spn, -sn);
        cp = cpn; sp = spn; cn = cnn; sn = snn;
      }
    } else {
      const unsigned short* xc = &xs[half*64*130 + idx];
      #pragma unroll 4
      for (int j=0; j<32; ++j){
        float xe = bf2f(xc[(2*j  )*130]);
        float xo = bf2f(xc[(2*j+1)*130]);
#define PARITY 0
        K1_ACCUM(xe, cp, sp)
#undef PARITY
#define PARITY 1
        K1_ACCUM(xo, cn, sn)
#undef PARITY
        float cpn = fmaf(K1CH, cn, -cp);
        float spn = fmaf(K1CH, sn, -sp);
        float cnn = fmaf(K1CH, cpn, -cn);
        float snn = fmaf(K1CH, spn, -sn);
        cp = cpn; sp = spn; cn = cnn; sn = snn;
      }
    }
#undef K1_ACCUM
  }
  __syncthreads();     // xs reads done; scratch may overwrite

  const int scrbase = (isRow ? 0 : SM_SCRG) + idx*15;
  if (half){
    #pragma unroll
    for (int i=0;i<14;++i) smem[scrbase+i] = acc[i];
  }
  __syncthreads();
  if (!half){
    #pragma unroll
    for (int i=0;i<14;++i) acc[i] += smem[scrbase+i];
    float A0e=acc[0],A0o=acc[1],Ce1=acc[2],Se1=acc[3],Co1=acc[4],So1=acc[5],
          Ce2=acc[6],Se2=acc[7],Co2=acc[8],So2=acc[9],
          Ce3=acc[10],Se3=acc[11],Co3=acc[12],So3=acc[13];
    float d0  = A0e-A0o;
    float dc1 = Ce1-Co1, ds1 = Se1-So1;
    float dc2 = Ce2-Co2, ds2 = Se2-So2;
    float dc3 = Ce3-Co3, ds3 = Se3-So3;
    float* gp = ghb + (isRow ? 1536 : 0);
    const int k = idx;
    gp[(0*2+0)*128+k] = dc3*INV_SQRT128;  gp[(0*2+1)*128+k] =  ds3*INV_SQRT128;
    gp[(1*2+0)*128+k] = dc2*INV_SQRT128;  gp[(1*2+1)*128+k] =  ds2*INV_SQRT128;
    gp[(2*2+0)*128+k] = dc1*INV_SQRT128;  gp[(2*2+1)*128+k] =  ds1*INV_SQRT128;
    gp[(3*2+0)*128+k] = d0 *INV_SQRT128;  gp[(3*2+1)*128+k] =  0.f;
    gp[(4*2+0)*128+k] = dc1*INV_SQRT128;  gp[(4*2+1)*128+k] = -ds1*INV_SQRT128;
    gp[(5*2+0)*128+k] = dc2*INV_SQRT128;  gp[(5*2+1)*128+k] = -ds2*INV_SQRT128;
    if (isRow){
      smem[SM_HLR + 0*128 + k] = A0e+A0o;
      smem[SM_HLR + 1*128 + k] = Ce1+Co1;
      smem[SM_HLR + 2*128 + k] = Ce2+Co2;
      smem[SM_HLR + 3*128 + k] = Ce3+Co3;
      smem[SM_HLI + 0*128 + k] = -(Se1+So1);
      smem[SM_HLI + 1*128 + k] = -(Se2+So2);
      smem[SM_HLI + 2*128 + k] = -(Se3+So3);
    } else {
      smem[SM_GG + (0*2+0)*128 + k] = dc3;  smem[SM_GG + (0*2+1)*128 + k] = ds3;
      smem[SM_GG + (1*2+0)*128 + k] = dc2;  smem[SM_GG + (1*2+1)*128 + k] = ds2;
      smem[SM_GG + (2*2+0)*128 + k] = dc1;  smem[SM_GG + (2*2+1)*128 + k] = ds1;
      smem[SM_GG + (3*2+0)*128 + k] = d0;   smem[SM_GG + (3*2+1)*128 + k] = 0.f;
    }
  }
  __syncthreads();

  // ---- Fc tail: 36 outputs x 4 chunks ----
  if (tid < 144){
    int out = tid >> 2, chunk = tid & 3;
    int wi = out/6, zi = out%6, z = 61+zi;
    int wsrc = (wi<4) ? wi : (wi==4 ? 2 : 1);
    float isg = (wi<4) ? 1.f : -1.f;
    float fR=0.f, fI=0.f;
    const int cEnd = chunk*32 + 32;
    for (int c=chunk*32; c<cEnd; ++c){
      float gR = smem[SM_GG + (wsrc*2  )*128 + c];
      float gI = isg*smem[SM_GG + (wsrc*2+1)*128 + c];
      int m = (z*c) & 127;
      float ts, tc; __sincosf((float)m*C128, &ts, &tc);
      fR += gR*tc + gI*ts;
      fI += gI*tc - gR*ts;
    }
    fR += __shfl_xor(fR,1); fI += __shfl_xor(fI,1);
    fR += __shfl_xor(fR,2); fI += __shfl_xor(fI,2);
    if (chunk==0){
      ghb[3072 + out*2]     = fR * INV128;
      ghb[3072 + out*2 + 1] = fI * INV128;
    }
  }
  // ---- magC tail: 49 outputs x 4 chunks ----
  if (tid >= 256 && tid < 452){
    int i = (tid-256) >> 2, chunk = (tid-256) & 3;
    int u = i/7 - 3, v = i%7 - 3;
    int va = v < 0 ? -v : v;
    float vsg = v < 0 ? -1.f : 1.f;
    float fR=0.f, fI=0.f;
    const int rEnd = chunk*32 + 32;
    for (int r=chunk*32; r<rEnd; ++r){
      float hR = smem[SM_HLR + va*128 + r];
      float hI = (va==0) ? 0.f : vsg*smem[SM_HLI + (va-1)*128 + r];
      int m = ((u*r) % 128 + 128) & 127;
      float ts, tc; __sincosf((float)m*C128, &ts, &tc);
      fR += hR*tc + hI*ts;
      fI += hI*tc - hR*ts;
    }
    fR += __shfl_xor(fR,1); fI += __shfl_xor(fI,1);
    fR += __shfl_xor(fR,2); fI += __shfl_xor(fI,2);
    if (chunk==0){
      fR *= INV128; fI *= INV128;
      ghb[3144 + i] = sqrtf(fR*fR + fI*fI);
    }
  }
}

// =====================================================================
// K_mlp
// =====================================================================
__global__ void __launch_bounds__(64) K_mlp(const float* __restrict__ GH,
                                            const float* __restrict__ w1,
                                            const float* __restrict__ b1,
                                            const float* __restrict__ w2,
                                            const float* __restrict__ b2,
                                            float* __restrict__ kern){
  __shared__ float flat[49];
  __shared__ float hh[32];
  const int b = blockIdx.x, tid = threadIdx.x;
  if (tid < 49){
    float s = 0.f;
    for (int c=0; c<256; ++c)
      s += GH[(size_t)(b*256 + c)*GH_STRIDE + 3144 + tid];
    flat[tid] = s * (1.0f/256.0f);
  }
  __syncthreads();
  if (tid < 32){
    float s = b1[tid];
    for (int i=0; i<49; ++i) s += flat[i]*w1[tid*49+i];
    hh[tid] = fmaxf(s, 0.f);
  }
  __syncthreads();
  if (tid == 0){
    float p[3];
    #pragma unroll
    for (int k=0; k<3; ++k){
      float s = b2[k];
      for (int j=0; j<32; ++j) s += hh[j]*w2[k*32+j];
      p[k] = s;
    }
    float theta = atan2f(p[0], p[1])*0.5f + 1.57079632679489662f;
    float ct = cosf(theta), st = sinf(theta);
    float l1 = expf(p[2]);
    float l2 = 1.0f/(l1 + 1e-8f);
    float inv1 = 1.0f/(2.0f*l1*l1);
    float inv2 = 1.0f/(2.0f*l2*l2);
    float sum = 0.f;
    for (int i=0; i<7; ++i) for (int j=0; j<7; ++j){
      float yy = (float)(i-3), xx = (float)(j-3);
      float xr =  xx*ct + yy*st;
      float yr = -xx*st + yy*ct;
      sum += expf(-(xr*xr*inv1 + yr*yr*inv2));
    }
    float inv = 1.0f/(sum + 1e-8f);
    for (int i=0; i<7; ++i) for (int j=0; j<7; ++j){
      float yy = (float)(i-3), xx = (float)(j-3);
      float xr =  xx*ct + yy*st;
      float yr = -xx*st + yy*ct;
      kern[b*49 + i*7 + j] = expf(-(xr*xr*inv1 + yr*yr*inv2)) * inv;
    }
  }
}

// =====================================================================
// K3: per batch: kappa/lambda tables + W field
// =====================================================================
__global__ void __launch_bounds__(256) K3(const float* __restrict__ kern,
                                          float* __restrict__ KL,
                                          float* __restrict__ W){
  __shared__ float twc[128], tws[128], kl[49];
  __shared__ float kapl[7][2][128];
  const int b = blockIdx.x, tid = threadIdx.x;
  if (tid < 128){
    float s,c; __sincosf((float)tid*C128, &s, &c);
    twc[tid]=c; tws[tid]=s;
  }
  if (tid < 49) kl[tid] = kern[b*49 + tid];
  __syncthreads();
  if (tid < 128){
    const int c = tid;
    float* klb = KL + (size_t)b*3584;
    #pragma unroll
    for (int dp=0; dp<7; ++dp){
      float kR=0.f, kI=0.f;
      #pragma unroll
      for (int dq=0; dq<7; ++dq){
        int m = (((dq-3)*c) % 128 + 128) & 127;
        float kv = kl[dp*7+dq];
        kR += kv*twc[m]; kI -= kv*tws[m];
      }
      klb[(dp*2  )*128 + c] = kR;
      klb[(dp*2+1)*128 + c] = kI;
      kapl[dp][0][c] = kR; kapl[dp][1][c] = kI;
    }
    const int r = tid;
    #pragma unroll
    for (int dq=0; dq<7; ++dq){
      float lR=0.f, lI=0.f;
      #pragma unroll
      for (int dp=0; dp<7; ++dp){
        int m = (((dp-3)*r) % 128 + 128) & 127;
        float kv = kl[dp*7+dq];
        lR += kv*twc[m]; lI -= kv*tws[m];
      }
      klb[1792 + (dq*2  )*128 + r] = lR;
      klb[1792 + (dq*2+1)*128 + r] = lI;
    }
  }
  __syncthreads();
  for (int k=0;k<64;++k){
    int px = k*256 + tid;
    int r = px >> 7, c = px & 127;
    float w = 0.f;
    #pragma unroll
    for (int dp=0; dp<7; ++dp){
      int m = (((dp-3)*r) % 128 + 128) & 127;
      w += twc[m]*kapl[dp][0][c] + tws[m]*kapl[dp][1][c];
    }
    W[(size_t)b*IMG + px] = w;
  }
}

// =====================================================================
// K_tab: per image: Abar (corner-folded) and Bbar tables
// =====================================================================
__global__ void __launch_bounds__(128) K_tab(const float* __restrict__ GH,
                                             const float* __restrict__ KL,
                                             const float* __restrict__ kern,
                                             float* __restrict__ AB){
  __shared__ float dRe[36], dIm[36], kl[49];
  const int tid = threadIdx.x;
  const int img = blockIdx.x, b = img >> 8;
  const float* ghb = GH + (size_t)img*GH_STRIDE;
  const float* klb = KL + (size_t)b*3584;
  float* abb = AB + (size_t)img*AB_STRIDE;

  if (tid < 49) kl[tid] = kern[b*49 + tid];
  __syncthreads();
  if (tid < 36){
    int si = tid/6, ti = tid%6;
    float dR=0.f, dI=0.f;
    for (int j=0; j<c_pcnt[si]; ++j){
      int dp = c_pdp0[si] + j;
      int wi = (si-3) + dp;
      for (int l=0; l<c_pcnt[ti]; ++l){
        int dq = c_pdp0[ti] + l;
        int zi = (ti-3) + dq;
        float kv = kl[dp*7+dq];
        dR += kv * ghb[3072 + (wi*6+zi)*2];
        dI += kv * ghb[3072 + (wi*6+zi)*2 + 1];
      }
    }
    dRe[tid] = dR; dIm[tid] = dI;
  }
  __syncthreads();

  const int c = tid;
  float s1,c1; __sincosf((float)c*C128, &s1, &c1);
  float c2 = c1*c1 - s1*s1, s2 = 2.f*c1*s1;
  float c3 = c1*c2 - s1*s2, s3 = s1*c2 + c1*s2;
  float ct[6] = {c3,c2,c1,1.f,c1,c2};
  float st[6] = {-s3,-s2,-s1,0.f,s1,s2};
  float sgnc = (c & 1) ? -1.f : 1.f;

  float gr[6], gi[6], kr[7], ki[7];
  #pragma unroll
  for (int w=0;w<6;++w){ gr[w]=ghb[(w*2)*128+c]; gi[w]=ghb[(w*2+1)*128+c]; }
  #pragma unroll
  for (int dp=0;dp<7;++dp){ kr[dp]=klb[(dp*2)*128+c]; ki[dp]=klb[(dp*2+1)*128+c]; }

  #pragma unroll
  for (int si=0; si<6; ++si){
    float dR=0.f, dI=0.f;
    for (int j=0; j<c_pcnt[si]; ++j){
      int dp = c_pdp0[si] + j;
      int w = (si-3) + dp;
      dR += kr[dp]*gr[w] - ki[dp]*gi[w];
      dI += kr[dp]*gi[w] + ki[dp]*gr[w];
    }
    float corrR=0.f, corrI=0.f;
    #pragma unroll
    for (int ti=0; ti<6; ++ti){
      float DR = dRe[si*6+ti], DI = dIm[si*6+ti];
      corrR += DR*ct[ti] - DI*st[ti];
      corrI += DR*st[ti] + DI*ct[ti];
    }
    abb[(si*2  )*128 + c] = INV_SQRT128*dR - INV128*sgnc*corrR;
    abb[(si*2+1)*128 + c] = INV_SQRT128*dI - INV128*sgnc*corrI;
  }

  const int r = tid;
  float hr[6], hi_[6], lr[7], li[7];
  #pragma unroll
  for (int z=0;z<6;++z){ hr[z]=ghb[1536+(z*2)*128+r]; hi_[z]=ghb[1536+(z*2+1)*128+r]; }
  #pragma unroll
  for (int dq=0;dq<7;++dq){ lr[dq]=klb[1792+(dq*2)*128+r]; li[dq]=klb[1792+(dq*2+1)*128+r]; }
  #pragma unroll
  for (int ti=0; ti<6; ++ti){
    float bR=0.f, bI=0.f;
    for (int l=0; l<c_pcnt[ti]; ++l){
      int dq = c_pdp0[ti] + l;
      int z = (ti-3) + dq;
      bR += lr[dq]*hr[z] - li[dq]*hi_[z];
      bI += lr[dq]*hi_[z] + li[dq]*hr[z];
    }
    abb[1536 + r*12 + ti*2]     = INV_SQRT128*bR;
    abb[1536 + r*12 + ti*2 + 1] = INV_SQRT128*bI;
  }
}

// =====================================================================
// K4: per image: filt = x*W - E  (bf16 out), float2 per lane
// =====================================================================
__global__ void __launch_bounds__(256) K4(const float* __restrict__ xlow,
                                          const float* __restrict__ W,
                                          const float* __restrict__ AB,
                                          unsigned short* __restrict__ filt){
  const int tid = threadIdx.x;
  const int img = blockIdx.x, b = img >> 8;
  const int c0 = (tid & 63)*2, grp = tid >> 6;
  const float* abb = AB + (size_t)img*AB_STRIDE;
  const float* xim = xlow + (size_t)img*IMG;
  const float* Wb  = W + (size_t)b*IMG;
  unsigned short* fim = filt + (size_t)img*IMG;

  float ar[2][6], ai[2][6], ctc[2][6], stc[2][6];
  #pragma unroll
  for (int col=0; col<2; ++col){
    int c = c0 + col;
    #pragma unroll
    for (int si=0;si<6;++si){ ar[col][si]=abb[(si*2)*128+c]; ai[col][si]=abb[(si*2+1)*128+c]; }
    float s1,c1; __sincosf((float)c*C128, &s1, &c1);
    float c2 = c1*c1 - s1*s1, s2 = 2.f*c1*s1;
    float c3 = c1*c2 - s1*s2, s3 = s1*c2 + c1*s2;
    ctc[col][0]=c3; ctc[col][1]=c2; ctc[col][2]=c1; ctc[col][3]=1.f; ctc[col][4]=c1; ctc[col][5]=c2;
    stc[col][0]=-s3; stc[col][1]=-s2; stc[col][2]=-s1; stc[col][3]=0.f; stc[col][4]=s1; stc[col][5]=s2;
  }

  for (int k=0;k<32;++k){
    int ru = __builtin_amdgcn_readfirstlane(grp*32 + k);
    const float* brow = abb + 1536 + ru*12;
    float4 b0 = *(const float4*)(brow);
    float4 b1 = *(const float4*)(brow+4);
    float4 b2 = *(const float4*)(brow+8);
    float rs1,rc1; __sincosf((float)ru*C128, &rs1, &rc1);
    float rc2 = rc1*rc1 - rs1*rs1, rs2 = 2.f*rc1*rs1;
    float rc3 = rc1*rc2 - rs1*rs2, rs3 = rs1*rc2 + rc1*rs2;
    float rcs[6] = {rc3,rc2,rc1,1.f,rc1,rc2};
    float rss[6] = {-rs3,-rs2,-rs1,0.f,rs1,rs2};

    float ER0 = 0.f, ER1 = 0.f;
    #pragma unroll
    for (int si=0;si<6;++si){
      ER0 += rcs[si]*ar[0][si] - rss[si]*ai[0][si];
      ER1 += rcs[si]*ar[1][si] - rss[si]*ai[1][si];
    }
    float rsg = (ru & 1) ? -1.f : 1.f;
    ER0 *= rsg; ER1 *= rsg;

    float bRv[6] = {b0.x, b0.z, b1.x, b1.z, b2.x, b2.z};
    float bIv[6] = {b0.y, b0.w, b1.y, b1.w, b2.y, b2.w};
    float EC0 = 0.f, EC1 = 0.f;
    #pragma unroll
    for (int ti=0;ti<6;++ti){
      EC0 += ctc[0][ti]*bRv[ti] - stc[0][ti]*bIv[ti];
      EC1 += ctc[1][ti]*bRv[ti] - stc[1][ti]*bIv[ti];
    }
    int px = ru*128 + c0;
    float2 xv = *(const float2*)(&xim[px]);
    float2 wv = *(const float2*)(&Wb[px]);
    float v0 = xv.x*wv.x - ER0 - EC0;
    float v1 = xv.y*wv.y - ER1 + EC1;
    unsigned int pack = ((unsigned int)f2bf(v1) << 16) | (unsigned int)f2bf(v0);
    *(unsigned int*)(&fim[px]) = pack;
  }
}

// =====================================================================
// K_w: refine_w f32 -> bf16
// =====================================================================
__global__ void __launch_bounds__(256) K_w(const float* __restrict__ rw,
                                           unsigned short* __restrict__ rwbf){
  int i = blockIdx.x*256 + threadIdx.x;
  rwbf[i] = f2bf(rw[i]);
}

// =====================================================================
// K_up: bilinear upsample x_high (64x64 -> 128x128) as bf16
// =====================================================================
__global__ void __launch_bounds__(256) K_up(const float* __restrict__ xhigh,
                                            unsigned short* __restrict__ up){
  __shared__ float xs[64*68];
  const int tid = threadIdx.x;
  const int img = blockIdx.x;
  const float* src = xhigh + (size_t)img*4096;
  unsigned short* dst = up + (size_t)img*IMG;

  #pragma unroll
  for (int p=0; p<4; ++p){
    int t = p*256 + tid;
    float4 v = ((const float4*)src)[t];
    int r = t >> 4, k = t & 15;
    *(float4*)(&xs[r*68 + k*4]) = v;
  }
  __syncthreads();

  for (int k=0; k<32; ++k){
    int pr = k*256 + tid;
    int y = pr >> 6, x0 = (pr & 63)*2;
    float fy = 0.5f*(float)y - 0.25f;
    int iyf = (int)floorf(fy);
    float ty = fy - (float)iyf;
    int iy0 = iyf < 0 ? 0 : iyf;
    int iy1 = (iyf+1) > 63 ? 63 : (iyf+1);
    float wy1 = ty, wy0 = 1.0f - ty;
    const float* r0 = &xs[iy0*68];
    const float* r1 = &xs[iy1*68];

    float outv[2];
    #pragma unroll
    for (int e=0; e<2; ++e){
      int x = x0 + e;
      float fx = 0.5f*(float)x - 0.25f;
      int ixf = (int)floorf(fx);
      float tx = fx - (float)ixf;
      int ix0 = ixf < 0 ? 0 : ixf;
      int ix1 = (ixf+1) > 63 ? 63 : (ixf+1);
      float wx1 = tx, wx0 = 1.0f - tx;
      outv[e] = wy0*(wx0*r0[ix0] + wx1*r0[ix1])
              + wy1*(wx0*r1[ix0] + wx1*r1[ix1]);
    }
    unsigned int pack = ((unsigned int)f2bf(outv[1]) << 16) | (unsigned int)f2bf(outv[0]);
    *(unsigned int*)(&dst[y*NW + x0]) = pack;
  }
}

// =====================================================================
// K_gemm: out[b,o,p] = sum_c rw[o,c]*filt[b,c,p] + up[b,o,p]
// Fused transpose + 2-step register prefetch (T14/T3): loads for step
// ks+2 are issued at iter ks, published to LDS at iter ks+1, consumed
// at iter ks+2 -> ~2 MFMA phases of HBM-latency cover. Fully unrolled;
// pf[][] indices static. Double-buffered LDS, 1 barrier per K-step.
// =====================================================================
__global__ void __launch_bounds__(256, 4) K_gemm(const unsigned short* __restrict__ rwbf,
                                                 const unsigned short* __restrict__ filt,
                                                 const unsigned short* __restrict__ up,
                                                 float* __restrict__ out){
  __shared__ unsigned short At[2][128*40];
  __shared__ unsigned short Bt[2][128*40];
  const int tid = threadIdx.x, lane = tid & 63, wv = tid >> 6;
  const int wr = wv >> 1, wc = wv & 1;
  const int xg = blockIdx.x;
  const int g16 = xg >> 4, i16 = xg & 15;
  const int ot = i16 >> 3, pt = (g16 << 3) | (i16 & 7);
  const int b = blockIdx.z;
  const int p0 = pt*128, o0 = ot*128;

  f32x4 acc[4][4];
  #pragma unroll
  for (int m=0;m<4;++m)
    #pragma unroll
    for (int n=0;n<4;++n){ f32x4 z = {0.f,0.f,0.f,0.f}; acc[m][n] = z; }

  // A staging: rwbf[o][c] row-major, k-contiguous
  const int arow  = tid >> 2;          // 0..63
  const int akoff = (tid & 3) * 8;     // u16 offset, 0..24
  const unsigned short* aP0 = &rwbf[(size_t)(o0+arow   )*256 + akoff];
  const unsigned short* aP1 = &rwbf[(size_t)(o0+arow+64)*256 + akoff];

  // B staging: filt[b][c][p]; thread loads channel pair (bc2, bc2+1),
  // 8 p's, repacks to transposed u32 writes.
  const int bc2 = (tid & 15) * 2;      // 0..30 (even channel in k-tile)
  const int bpo = (tid >> 4) * 8;      // p offset within tile, 0..120
  const unsigned short* bP0 = &filt[((size_t)b*NC + bc2    )*IMG + p0 + bpo];
  const unsigned short* bP1 = &filt[((size_t)b*NC + bc2 + 1)*IMG + p0 + bpo];

  // pf[s][0..3] = {av0, av1, bv0, bv1}
  i32x4 pf[2][4];

#define LOAD_STEP(S, KS)                                                     \
  {                                                                          \
    pf[S][0] = *(const i32x4*)(aP0 + (KS)*32);                               \
    pf[S][1] = *(const i32x4*)(aP1 + (KS)*32);                               \
    pf[S][2] = *(const i32x4*)(bP0 + (size_t)(KS)*32*IMG);                   \
    pf[S][3] = *(const i32x4*)(bP1 + (size_t)(KS)*32*IMG);                   \
  }

#define STORE_STEP(BUF, S)                                                   \
  {                                                                          \
    *(i32x4*)(&At[BUF][ arow    *40 + akoff]) = pf[S][0];                    \
    *(i32x4*)(&At[BUF][(arow+64)*40 + akoff]) = pf[S][1];                    \
    _Pragma("unroll")                                                        \
    for (int j=0;j<4;++j){                                                   \
      unsigned int w0 = (unsigned int)pf[S][2][j];                           \
      unsigned int w1 = (unsigned int)pf[S][3][j];                           \
      unsigned int lo = (w0 & 0xffffu) | (w1 << 16);                         \
      unsigned int hi = (w0 >> 16) | (w1 & 0xffff0000u);                     \
      *(unsigned int*)(&Bt[BUF][(bpo+2*j  )*40 + bc2]) = lo;                 \
      *(unsigned int*)(&Bt[BUF][(bpo+2*j+1)*40 + bc2]) = hi;                 \
    }                                                                        \
  }

  LOAD_STEP(0, 0)
  LOAD_STEP(1, 1)
  STORE_STEP(0, 0)
  __syncthreads();

  const int g = lane >> 4, r16 = lane & 15;
  #pragma unroll
  for (int ks=0; ks<8; ++ks){
    const int cur = ks & 1, nxt = cur ^ 1;
    if (ks < 6) LOAD_STEP(cur, ks+2)           // pf[cur] is dead (stored last iter)
    bf16x8 af[4], bfr[4];
    #pragma unroll
    for (int m=0;m<4;++m) af[m]  = *(const bf16x8*)(&At[cur][(wr*64 + m*16 + r16)*40 + g*8]);
    #pragma unroll
    for (int n=0;n<4;++n) bfr[n] = *(const bf16x8*)(&Bt[cur][(wc*64 + n*16 + r16)*40 + g*8]);
    #pragma unroll
    for (int m=0;m<4;++m)
      #pragma unroll
      for (int n=0;n<4;++n)
        acc[m][n] = __builtin_amdgcn_mfma_f32_16x16x32_bf16(af[m], bfr[n], acc[m][n], 0, 0, 0);
    if (ks < 7){
      STORE_STEP(nxt, nxt)                     // publish step ks+1 (loaded >=1 iter ago)
      __syncthreads();
    }
  }
#undef LOAD_STEP
#undef STORE_STEP

  // epilogue: out = acc + up (same-address coalesced load/store)
  const int y = pt;
  #pragma unroll
  for (int m=0;m<4;++m){
    #pragma unroll
    for (int j=0;j<4;++j){
      int o = o0 + wr*64 + m*16 + g*4 + j;
      size_t base = (size_t)(b*NC + o)*IMG + (size_t)y*NW;
      #pragma unroll
      for (int n=0;n<4;++n){
        int xcol = wc*64 + n*16 + r16;
        float upv = bf2f(up[base + xcol]);
        out[base + xcol] = acc[m][n][j] + upv;
      }
    }
  }
}

// =====================================================================
extern "C" void kernel_launch(void* const* d_in, const int* in_sizes, int n_in,
                              void* d_out, int out_size, void* d_ws, size_t ws_size,
                              hipStream_t stream){
  (void)in_sizes; (void)n_in; (void)out_size; (void)ws_size;
  const float* xhigh = (const float*)d_in[0];
  const float* xlow  = (const float*)d_in[1];
  const float* w1    = (const float*)d_in[2];
  const float* b1    = (const float*)d_in[3];
  const float* w2    = (const float*)d_in[4];
  const float* b2    = (const float*)d_in[5];
  const float* rw    = (const float*)d_in[6];

  char* ws = (char*)d_ws;
  unsigned short* filt  = (unsigned short*)(ws);                    // 67,108,864
  unsigned short* up    = (unsigned short*)(ws + 67108864);         // 67,108,864
  float* GH   = (float*)(ws + 134217728);                           // 26,214,400
  float* AB   = (float*)(ws + 160432128);                           // 25,165,824
  float* kern = (float*)(ws + 185597952);                           // 4,096 (pad)
  float* KL   = (float*)(ws + 185602048);                           // 114,688
  float* Wf   = (float*)(ws + 185716736);                           // 524,288
  unsigned short* rwbf = (unsigned short*)(ws + 186241024);         // 131,072

  K1   <<<NIMG, 512, 0, stream>>>(xlow, GH);
  K_mlp<<<NB,   64,  0, stream>>>(GH, w1, b1, w2, b2, kern);
  K3   <<<NB,   256, 0, stream>>>(kern, KL, Wf);
  K_w  <<<256,  256, 0, stream>>>(rw, rwbf);
  K_tab<<<NIMG, 128, 0, stream>>>(GH, KL, kern, AB);
  K4   <<<NIMG, 256, 0, stream>>>(xlow, Wf, AB, filt);
  K_up <<<NIMG, 256, 0, stream>>>(xhigh, up);
  K_gemm <<<dim3(256, 1, NB), 256, 0, stream>>>(rwbf, filt, up, (float*)d_out);
}